// Round 2
// baseline (591.836 us; speedup 1.0000x reference)
//
#include <hip/hip_runtime.h>
#include <hip/hip_bf16.h>

// PhysicsGraphFusion: B=1024, N=7, D=1024
// Outputs (flat): fused (B*D), updated (B*N*D), imp (B*N), attn (B*N*N), phys (1), align (1)

typedef __attribute__((ext_vector_type(8))) short bf16x8;
typedef __attribute__((ext_vector_type(4))) float f32x4;

__constant__ float c_adj[49] = {
    1,1,0,0,1,1,1,
    1,1,1,1,1,1,1,
    0,1,1,0,1,0,1,
    0,1,0,1,1,1,1,
    1,1,1,1,1,1,1,
    1,1,0,1,1,1,1,
    1,1,1,1,1,1,1};

__device__ __forceinline__ float gelu_f(float x) {
    return 0.5f * x * (1.0f + erff(x * 0.7071067811865476f));
}
__device__ __forceinline__ float b2f(unsigned short u) {
    unsigned int x = ((unsigned int)u) << 16;
    union { unsigned int i; float f; } c; c.i = x; return c.f;
}
__device__ __forceinline__ unsigned short f2b(float f) {
    __hip_bfloat16 h = __float2bfloat16(f);
    union { __hip_bfloat16 b; unsigned short u; } c; c.b = h; return c.u;
}

__device__ __forceinline__ void gload_lds16(const void* g, void* l) {
    __builtin_amdgcn_global_load_lds(
        (const __attribute__((address_space(1))) unsigned int*)g,
        (__attribute__((address_space(3))) unsigned int*)l, 16, 0, 0);
}

// row mapping: 0: r->r ; 1: r->r*7+6 (ctx rows) ; 2: r->r-r%7+6 (ctx broadcast)
__device__ __forceinline__ int maprow(int r, int mode) {
    if (mode == 1) return r * 7 + 6;
    if (mode == 2) return r - r % 7 + 6;
    return r;
}

// ---------------------------------------------------------------------------
// 256x256-tile, 512-thread, counted-vmcnt phased GEMM (T2+T3+T4+T5).
// C[M x N] = A[M x K] @ WT^T + bias, output bf16 segmented (seg = c>>10).
// K-tiles of 32. LDS: 4-slot ring per operand (4 x 256x32 bf16 A + same B
// = 128 KB). Two phases per K-tile (16 MFMA each). Per phase: ds_read frags
// of tile kt, issue staging of one unit (A or B) of tile kt+2, barrier,
// MFMA. vmcnt(4) at odd-phase end guarantees tile kt+1 landed while tile
// kt+2's 4 loads stay in flight (never drains to 0 in steady state).
// Race proof: slot written at phase g was last ds_read at phase g-3; the
// per-phase barriers keep all waves within one phase window, so all its
// readers are done. Tail: last two tiles use vmcnt(0).
// Chunk swizzle: LDS chunk = global chunk ^ ((row>>1)&3)  (measured 0
// bank conflicts in the 128^2 kernel; same row-stride 64B layout).
// ---------------------------------------------------------------------------
__global__ __launch_bounds__(512) void gemm256(
    const unsigned short* __restrict__ A,
    const unsigned short* __restrict__ WT, int ldw,
    const float* __restrict__ bias,
    unsigned short* __restrict__ Cb, size_t segStride,
    int K)
{
    __shared__ short As[4 * 256 * 32];   // 64 KB
    __shared__ short Bs[4 * 256 * 32];   // 64 KB

    const int tid  = threadIdx.x;
    const int lane = tid & 63;
    const int w    = tid >> 6;           // wave 0..7
    const int wm   = w >> 2;             // 0..1  -> rows wm*128
    const int wn   = w & 3;              // 0..3  -> cols wn*64
    const int wmr  = wm * 128;
    const int wnr  = wn * 64;

    // bijective XCD swizzle (grid 20x28 = 560, 560 % 8 == 0)
    int lin = blockIdx.y * gridDim.x + blockIdx.x;
    const int nwg = gridDim.x * gridDim.y;
    const int cpx = nwg >> 3;
    lin = (lin & 7) * cpx + (lin >> 3);
    const int row0 = (lin / gridDim.x) * 256;
    const int col0 = (lin % gridDim.x) * 256;

    const int fr  = lane & 15;
    const int fko = (((lane >> 4) ^ ((fr >> 1) & 3)) << 3);   // swizzled chunk (shorts)

    // staging geometry: per unit, 2 loads/thread; seg s = ld*512+tid
    // covers 256 rows x 4 chunks. Precompute per-ld constants.
    int srow[2], skc[2], ldsoff[2];
    #pragma unroll
    for (int ld = 0; ld < 2; ++ld) {
        int s = ld * 512 + tid;
        int r = s >> 2, ch = s & 3;
        srow[ld]   = r;
        skc[ld]    = (ch ^ ((r >> 1) & 3)) * 8;   // pre-swizzled global chunk
        ldsoff[ld] = s * 8;                        // linear LDS dest (shorts)
    }

    const int NT = K >> 5;   // K-tiles of 32

    f32x4 acc[8][4] = {};
    bf16x8 af[4], bf_[4];

    // ---- prologue: issue units 0..3 (tiles 0,1: A then B), wait tile 0 ----
    #pragma unroll
    for (int u0 = 0; u0 < 4; ++u0) {
        int tu = u0 >> 1, slot = tu;
        #pragma unroll
        for (int ld = 0; ld < 2; ++ld) {
            if ((u0 & 1) == 0)
                gload_lds16(A + (size_t)(row0 + srow[ld]) * K + tu * 32 + skc[ld],
                            &As[slot * 8192 + ldsoff[ld]]);
            else
                gload_lds16(WT + (size_t)(col0 + srow[ld]) * ldw + tu * 32 + skc[ld],
                            &Bs[slot * 8192 + ldsoff[ld]]);
        }
    }
    asm volatile("s_waitcnt vmcnt(4)" ::: "memory");   // units 0,1 (tile 0) landed
    asm volatile("s_barrier" ::: "memory");

    // ---- main loop: NT tiles x 2 phases ----
    for (int kt = 0; kt < NT; ++kt) {
        const short* Ab = &As[(kt & 3) * 8192];
        const short* Bb = &Bs[(kt & 3) * 8192];

        // ===== even phase (g = 2kt): mquad 0, read B =====
        {
            #pragma unroll
            for (int i = 0; i < 4; ++i)
                af[i] = *(const bf16x8*)(Ab + (wmr + i * 16 + fr) * 32 + fko);
            #pragma unroll
            for (int j = 0; j < 4; ++j)
                bf_[j] = *(const bf16x8*)(Bb + (wnr + j * 16 + fr) * 32 + fko);
            int u = 2 * kt + 4;                       // stage unit g+4
            if (u < 2 * NT) {
                int tu = u >> 1, slot = tu & 3;       // u even -> A of tile tu
                #pragma unroll
                for (int ld = 0; ld < 2; ++ld)
                    gload_lds16(A + (size_t)(row0 + srow[ld]) * K + tu * 32 + skc[ld],
                                &As[slot * 8192 + ldsoff[ld]]);
            }
            asm volatile("s_barrier" ::: "memory");
            asm volatile("s_waitcnt lgkmcnt(0)" ::: "memory");
            __builtin_amdgcn_s_setprio(1);
            #pragma unroll
            for (int i = 0; i < 4; ++i)
                #pragma unroll
                for (int j = 0; j < 4; ++j)
                    acc[i][j] = __builtin_amdgcn_mfma_f32_16x16x32_bf16(
                        af[i], bf_[j], acc[i][j], 0, 0, 0);
            __builtin_amdgcn_s_setprio(0);
            asm volatile("s_barrier" ::: "memory");
        }

        // ===== odd phase (g = 2kt+1): mquad 1, reuse B, counted vmcnt =====
        {
            #pragma unroll
            for (int i = 0; i < 4; ++i)
                af[i] = *(const bf16x8*)(Ab + (wmr + (4 + i) * 16 + fr) * 32 + fko);
            int u = 2 * kt + 5;                       // stage unit g+4
            if (u < 2 * NT) {
                int tu = u >> 1, slot = tu & 3;       // u odd -> B of tile tu
                #pragma unroll
                for (int ld = 0; ld < 2; ++ld)
                    gload_lds16(WT + (size_t)(col0 + srow[ld]) * ldw + tu * 32 + skc[ld],
                                &Bs[slot * 8192 + ldsoff[ld]]);
            }
            // tile kt+1 must be landed after this barrier; tile kt+2's 4
            // loads may stay in flight (counted vmcnt, T4)
            if (kt >= NT - 2) asm volatile("s_waitcnt vmcnt(0)" ::: "memory");
            else              asm volatile("s_waitcnt vmcnt(4)" ::: "memory");
            asm volatile("s_barrier" ::: "memory");
            asm volatile("s_waitcnt lgkmcnt(0)" ::: "memory");
            __builtin_amdgcn_s_setprio(1);
            #pragma unroll
            for (int i = 0; i < 4; ++i)
                #pragma unroll
                for (int j = 0; j < 4; ++j)
                    acc[4 + i][j] = __builtin_amdgcn_mfma_f32_16x16x32_bf16(
                        af[i], bf_[j], acc[4 + i][j], 0, 0, 0);
            __builtin_amdgcn_s_setprio(0);
            asm volatile("s_barrier" ::: "memory");
        }
    }

    // ---- epilogue: bias + bf16 segmented store ----
    const int qrow = (lane >> 4) * 4;
    const int qcol = lane & 15;
    #pragma unroll
    for (int mf = 0; mf < 8; ++mf) {
        int rbase = row0 + wmr + mf * 16 + qrow;
        #pragma unroll
        for (int nf = 0; nf < 4; ++nf) {
            int c = col0 + wnr + nf * 16 + qcol;
            float bv = bias ? bias[c] : 0.0f;
            int seg = c >> 10, c0 = c & 1023;
            #pragma unroll
            for (int reg = 0; reg < 4; ++reg) {
                int r = rbase + reg;
                Cb[(size_t)seg * segStride + (size_t)r * 1024 + c0] =
                    f2b(acc[mf][nf][reg] + bv);
            }
        }
    }
}

// ---------------------------------------------------------------------------
// 128x128-tile bf16 MFMA GEMM (chunk-swizzled, 0 bank conflicts measured).
// ---------------------------------------------------------------------------
__global__ __launch_bounds__(256) void gemm128(
    const unsigned short* __restrict__ A1, int a1Mode,
    const unsigned short* __restrict__ A2, int a2Mode,
    const unsigned short* __restrict__ WT, int ldw,
    const float* __restrict__ bias,
    const float* __restrict__ resid,
    float* __restrict__ Cf,
    unsigned short* __restrict__ Cb, size_t segStride,
    int K, int act)
{
    __shared__ short As[128 * 32];
    __shared__ short Bs[128 * 32];
    const int tid = threadIdx.x;
    const int lane = tid & 63;
    const int w = tid >> 6;
    const int wr = (w >> 1) * 64;
    const int wc = (w & 1) * 64;
    const int row0 = blockIdx.y * 128;
    const int col0 = blockIdx.x * 128;
    const int fr = lane & 15;
    const int fko = (((lane >> 4) ^ ((fr >> 1) & 3)) << 3);

    f32x4 acc[4][4] = {};

    for (int k0 = 0; k0 < K; k0 += 32) {
        const unsigned short* srcA; int mode; int kbase;
        if (k0 < 1024) { srcA = A1; mode = a1Mode; kbase = k0; }
        else           { srcA = A2; mode = a2Mode; kbase = k0 - 1024; }
        #pragma unroll
        for (int rnd = 0; rnd < 2; ++rnd) {
            int c = rnd * 256 + tid;
            int m = c >> 2, ch = c & 3;
            int kc = (ch ^ ((m >> 1) & 3)) * 8;
            int rr = maprow(row0 + m, mode);
            gload_lds16(srcA + (size_t)rr * 1024 + kbase + kc, &As[c * 8]);
        }
        #pragma unroll
        for (int rnd = 0; rnd < 2; ++rnd) {
            int c = rnd * 256 + tid;
            int n = c >> 2, ch = c & 3;
            int kc = (ch ^ ((n >> 1) & 3)) * 8;
            gload_lds16(WT + (size_t)(col0 + n) * ldw + k0 + kc, &Bs[c * 8]);
        }
        __syncthreads();
        bf16x8 af[4], bf_[4];
        #pragma unroll
        for (int i = 0; i < 4; ++i)
            af[i] = *(const bf16x8*)(&As[(wr + i * 16 + fr) * 32 + fko]);
        #pragma unroll
        for (int j = 0; j < 4; ++j)
            bf_[j] = *(const bf16x8*)(&Bs[(wc + j * 16 + fr) * 32 + fko]);
        #pragma unroll
        for (int i = 0; i < 4; ++i)
            #pragma unroll
            for (int j = 0; j < 4; ++j)
                acc[i][j] = __builtin_amdgcn_mfma_f32_16x16x32_bf16(
                    af[i], bf_[j], acc[i][j], 0, 0, 0);
        __syncthreads();
    }

    const int qrow = (lane >> 4) * 4;
    const int qcol = lane & 15;
    #pragma unroll
    for (int i = 0; i < 4; ++i) {
        int rbase = row0 + wr + i * 16 + qrow;
        #pragma unroll
        for (int j = 0; j < 4; ++j) {
            int c = col0 + wc + j * 16 + qcol;
            float bv = bias ? bias[c] : 0.0f;
            int seg = c >> 10, c0 = c & 1023;
            #pragma unroll
            for (int reg = 0; reg < 4; ++reg) {
                int r = rbase + reg;
                float vv = acc[i][j][reg] + bv;
                if (act) vv = gelu_f(vv);
                if (resid) vv += resid[(size_t)r * 1024 + c];
                if (Cf) Cf[(size_t)r * 1024 + c] = vv;
                if (Cb) Cb[(size_t)seg * segStride + (size_t)r * 1024 + c0] = f2b(vv);
            }
        }
    }
}

// ---------------------------------------------------------------------------
// 64x128-tile bf16 MFMA GEMM (only used for the small ctx GEMM).
// ---------------------------------------------------------------------------
__global__ __launch_bounds__(256) void gemm64x128(
    const unsigned short* __restrict__ A1, int a1Mode,
    const unsigned short* __restrict__ A2, int a2Mode,
    const unsigned short* __restrict__ WT, int ldw,
    const float* __restrict__ bias,
    const float* __restrict__ resid,
    float* __restrict__ Cf,
    unsigned short* __restrict__ Cb,
    int K, int act)
{
    __shared__ short As[64 * 32];
    __shared__ short Bs[128 * 32];
    const int tid = threadIdx.x;
    const int lane = tid & 63;
    const int w = tid >> 6;
    const int wc = w * 32;
    const int row0 = blockIdx.y * 64;
    const int col0 = blockIdx.x * 128;
    const int fr = lane & 15;
    const int fko = (((lane >> 4) ^ ((fr >> 1) & 3)) << 3);

    f32x4 acc[4][2] = {};

    for (int k0 = 0; k0 < K; k0 += 32) {
        const unsigned short* srcA; int mode; int kbase;
        if (k0 < 1024) { srcA = A1; mode = a1Mode; kbase = k0; }
        else           { srcA = A2; mode = a2Mode; kbase = k0 - 1024; }
        {
            int m = tid >> 2, ch = tid & 3;
            int kc = (ch ^ ((m >> 1) & 3)) * 8;
            int rr = maprow(row0 + m, mode);
            gload_lds16(srcA + (size_t)rr * 1024 + kbase + kc, &As[tid * 8]);
        }
        #pragma unroll
        for (int rnd = 0; rnd < 2; ++rnd) {
            int c = rnd * 256 + tid;
            int n = c >> 2, ch = c & 3;
            int kc = (ch ^ ((n >> 1) & 3)) * 8;
            gload_lds16(WT + (size_t)(col0 + n) * ldw + k0 + kc, &Bs[c * 8]);
        }
        __syncthreads();
        bf16x8 af[4], bf_[2];
        #pragma unroll
        for (int i = 0; i < 4; ++i)
            af[i] = *(const bf16x8*)(&As[(i * 16 + fr) * 32 + fko]);
        #pragma unroll
        for (int j = 0; j < 2; ++j)
            bf_[j] = *(const bf16x8*)(&Bs[(wc + j * 16 + fr) * 32 + fko]);
        #pragma unroll
        for (int i = 0; i < 4; ++i)
            #pragma unroll
            for (int j = 0; j < 2; ++j)
                acc[i][j] = __builtin_amdgcn_mfma_f32_16x16x32_bf16(
                    af[i], bf_[j], acc[i][j], 0, 0, 0);
        __syncthreads();
    }

    const int qrow = (lane >> 4) * 4;
    const int qcol = lane & 15;
    #pragma unroll
    for (int i = 0; i < 4; ++i) {
        int rbase = row0 + i * 16 + qrow;
        #pragma unroll
        for (int j = 0; j < 2; ++j) {
            int c = col0 + wc + j * 16 + qcol;
            float bv = bias ? bias[c] : 0.0f;
            #pragma unroll
            for (int reg = 0; reg < 4; ++reg) {
                int r = rbase + reg;
                float vv = acc[i][j][reg] + bv;
                if (act) vv = gelu_f(vv);
                if (resid) vv += resid[(size_t)r * 1024 + c];
                if (Cf) Cf[(size_t)r * 1024 + c] = vv;
                if (Cb) Cb[(size_t)r * 1024 + c] = f2b(vv);
            }
        }
    }
}

// fp32 -> bf16 elementwise cast
__global__ __launch_bounds__(256) void cast_f2b(
    const float* __restrict__ in, unsigned short* __restrict__ out, int n)
{
    int i = (blockIdx.x * 256 + threadIdx.x) * 4;
    if (i >= n) return;
    float4 v = *(const float4*)(in + i);
    ushort4 o;
    o.x = f2b(v.x); o.y = f2b(v.y); o.z = f2b(v.z); o.w = f2b(v.w);
    *(ushort4*)(out + i) = o;
}

// All weight transposes+casts in one dispatch. grid (32, 64, 9).
__global__ __launch_bounds__(256) void tcast_all(
    const float* __restrict__ Wq, const float* __restrict__ Wk,
    const float* __restrict__ Wv, const float* __restrict__ We1,
    const float* __restrict__ Wu1, const float* __restrict__ Wu2,
    const float* __restrict__ Wi1,
    unsigned short* __restrict__ WT_all, unsigned short* __restrict__ Wu1T,
    unsigned short* __restrict__ Wu2T, unsigned short* __restrict__ Wi1T)
{
    const int z = blockIdx.z;
    const float* src; unsigned short* dst; int R;
    switch (z) {
        case 0: src = Wq;            dst = WT_all;               R = 1024; break;
        case 1: src = Wk;            dst = WT_all + 1024 * 1024; R = 1024; break;
        case 2: src = Wv;            dst = WT_all + 2048 * 1024; R = 1024; break;
        case 3: src = We1;           dst = WT_all + 3072 * 1024; R = 1024; break;
        case 4: src = We1 + 1048576; dst = WT_all + 4096 * 1024; R = 1024; break;
        case 5: src = We1 + 2097152; dst = WT_all + 5120 * 1024; R = 1024; break;
        case 6: src = Wu1;           dst = Wu1T;                 R = 2048; break;
        case 7: src = Wu2;           dst = Wu2T;                 R = 1024; break;
        default: src = Wi1;          dst = Wi1T;                 R = 2048; break;
    }
    const int rt = blockIdx.y * 32;
    if (rt >= R) return;
    const int ct = blockIdx.x * 32;
    __shared__ float t[32][33];
    const int tx = threadIdx.x & 31, ty = threadIdx.x >> 5;
    #pragma unroll
    for (int s = 0; s < 4; ++s)
        t[ty + s * 8][tx] = src[(size_t)(rt + ty + s * 8) * 1024 + ct + tx];
    __syncthreads();
    #pragma unroll
    for (int s = 0; s < 4; ++s)
        dst[(size_t)(ct + ty + s * 8) * R + rt + tx] = f2b(t[tx][ty + s * 8]);
}

// bias_all[5120] = [bq | bk | bv | 0 | 0]
__global__ void build_bias(const float* __restrict__ bq,
                           const float* __restrict__ bk,
                           const float* __restrict__ bv,
                           float* __restrict__ bias_all)
{
    int i = blockIdx.x * 256 + threadIdx.x;
    if (i >= 5120) return;
    int seg = i >> 10, c = i & 1023;
    float v = 0.f;
    if (seg == 0) v = bq[c];
    else if (seg == 1) v = bk[c];
    else if (seg == 2) v = bv[c];
    bias_all[i] = v;
}

// ---------------------------------------------------------------------------
// One block per (b,n): edge MLP + logits + softmax + messages (bf16 in/out)
// msg may alias la (each block reads only its own la row, into regs first).
// ---------------------------------------------------------------------------
__global__ __launch_bounds__(256) void attn_msg_b(
    const unsigned short* __restrict__ q, const unsigned short* __restrict__ k,
    const unsigned short* __restrict__ v,
    const unsigned short* __restrict__ la, const unsigned short* __restrict__ rb,
    const float* __restrict__ cc,
    const float* __restrict__ We2, const float* __restrict__ be2,
    float* __restrict__ attn_out, unsigned short* __restrict__ msg)
{
    const int bn = blockIdx.x;
    const int b = bn / 7, n = bn % 7;
    const int tid = threadIdx.x;
    const int lane = tid & 63, wv = tid >> 6;
    const int d0 = tid * 4;
    __shared__ float red[8];
    __shared__ float sm[7];

    float qv[4], lav[4], ccv[4], wev[4];
    {
        ushort4 q4 = *(const ushort4*)(q + (size_t)bn * 1024 + d0);
        ushort4 l4 = *(const ushort4*)(la + (size_t)bn * 1024 + d0);
        float4 c4 = *(const float4*)(cc + (size_t)b * 1024 + d0);
        float4 w4 = *(const float4*)(We2 + d0);
        qv[0] = b2f(q4.x); qv[1] = b2f(q4.y); qv[2] = b2f(q4.z); qv[3] = b2f(q4.w);
        lav[0] = b2f(l4.x); lav[1] = b2f(l4.y); lav[2] = b2f(l4.z); lav[3] = b2f(l4.w);
        ccv[0] = c4.x; ccv[1] = c4.y; ccv[2] = c4.z; ccv[3] = c4.w;
        wev[0] = w4.x; wev[1] = w4.y; wev[2] = w4.z; wev[3] = w4.w;
    }
    for (int m = 0; m < 7; ++m) {
        ushort4 k4 = *(const ushort4*)(k  + (size_t)(b * 7 + m) * 1024 + d0);
        ushort4 r4 = *(const ushort4*)(rb + (size_t)(b * 7 + m) * 1024 + d0);
        float s1 = qv[0] * b2f(k4.x) + qv[1] * b2f(k4.y)
                 + qv[2] * b2f(k4.z) + qv[3] * b2f(k4.w);
        float s2 = gelu_f(lav[0] + b2f(r4.x) + ccv[0]) * wev[0]
                 + gelu_f(lav[1] + b2f(r4.y) + ccv[1]) * wev[1]
                 + gelu_f(lav[2] + b2f(r4.z) + ccv[2]) * wev[2]
                 + gelu_f(lav[3] + b2f(r4.w) + ccv[3]) * wev[3];
        #pragma unroll
        for (int off = 32; off > 0; off >>= 1) {
            s1 += __shfl_down(s1, off);
            s2 += __shfl_down(s2, off);
        }
        if (lane == 0) { red[wv * 2] = s1; red[wv * 2 + 1] = s2; }
        __syncthreads();
        if (tid == 0) {
            float d1 = red[0] + red[2] + red[4] + red[6];
            float d2 = red[1] + red[3] + red[5] + red[7];
            sm[m] = d1 * (1.0f / 32.0f) + d2 + be2[0]
                  + (c_adj[n * 7 + m] - 1.0f) * 10000.0f;
        }
        __syncthreads();
    }
    if (tid == 0) {
        float mx = sm[0];
        #pragma unroll
        for (int m = 1; m < 7; ++m) mx = fmaxf(mx, sm[m]);
        float e[7], s = 0.f;
        #pragma unroll
        for (int m = 0; m < 7; ++m) { e[m] = expf(sm[m] - mx); s += e[m]; }
        float inv = 1.0f / s;
        #pragma unroll
        for (int m = 0; m < 7; ++m) {
            float wgt = e[m] * inv;
            sm[m] = wgt;
            attn_out[(size_t)bn * 7 + m] = wgt;
        }
    }
    __syncthreads();
    float wr_[7];
    #pragma unroll
    for (int m = 0; m < 7; ++m) wr_[m] = sm[m];
    float s0 = 0.f, s1 = 0.f, s2 = 0.f, s3 = 0.f;
    #pragma unroll
    for (int m = 0; m < 7; ++m) {
        ushort4 v4 = *(const ushort4*)(v + (size_t)(b * 7 + m) * 1024 + d0);
        s0 += wr_[m] * b2f(v4.x); s1 += wr_[m] * b2f(v4.y);
        s2 += wr_[m] * b2f(v4.z); s3 += wr_[m] * b2f(v4.w);
    }
    ushort4 o;
    o.x = f2b(s0); o.y = f2b(s1); o.z = f2b(s2); o.w = f2b(s3);
    *(ushort4*)(msg + (size_t)bn * 1024 + d0) = o;
}

// imp_logits[r] = dot(H[r,:], w2) + b2[0]   (H bf16)
__global__ __launch_bounds__(256) void row_dot_b(
    const unsigned short* __restrict__ H, const float* __restrict__ w2,
    const float* __restrict__ b2, float* __restrict__ out)
{
    const int r = blockIdx.x;
    const int tid = threadIdx.x;
    const int lane = tid & 63, wv = tid >> 6;
    __shared__ float red[4];
    const int d0 = tid * 4;
    ushort4 h4 = *(const ushort4*)(H + (size_t)r * 1024 + d0);
    float4 w4 = *(const float4*)(w2 + d0);
    float s = b2f(h4.x) * w4.x + b2f(h4.y) * w4.y
            + b2f(h4.z) * w4.z + b2f(h4.w) * w4.w;
    #pragma unroll
    for (int off = 32; off > 0; off >>= 1) s += __shfl_down(s, off);
    if (lane == 0) red[wv] = s;
    __syncthreads();
    if (tid == 0) out[r] = red[0] + red[1] + red[2] + red[3] + b2[0];
}

// per-b: softmax over N, cap/redistribute, imp; fused = sum_n imp*updated
__global__ __launch_bounds__(256) void imp_fused_k(
    const float* __restrict__ logits, const float* __restrict__ upd,
    float* __restrict__ imp_out, float* __restrict__ fused_out)
{
    const int b = blockIdx.x;
    const int tid = threadIdx.x;
    __shared__ float w[7];
    if (tid == 0) {
        float l[7], e[7];
        float mx = -1e30f;
        for (int i = 0; i < 7; ++i) { l[i] = logits[b * 7 + i]; mx = fmaxf(mx, l[i]); }
        float s = 0.f;
        for (int i = 0; i < 7; ++i) { e[i] = expf(l[i] - mx); s += e[i]; }
        float inv = 1.0f / s;
        float imp[7];
        for (int i = 0; i < 7; ++i) imp[i] = e[i] * inv;
        const float cap[7] = {1.f, 1.f, 1.f, 0.26f, 1.f, 1.f, 0.24f};
        const float fr[7]  = {1.f, 1.f, 1.f, 0.f,   1.f, 1.f, 0.f};
        float capped[7], capsum = 0.f, fmass = 0.f;
        for (int i = 0; i < 7; ++i) {
            capped[i] = fminf(imp[i], cap[i]);
            capsum += capped[i];
            fmass += imp[i] * fr[i];
        }
        float residual = fmaxf(1.0f - capsum, 0.0f);
        float redis[7], rs = 0.f;
        for (int i = 0; i < 7; ++i) {
            float fs = (fmass > 1e-6f) ? imp[i] * fr[i] / fmaxf(fmass, 1e-6f)
                                       : fr[i] * 0.2f;
            redis[i] = capped[i] + fs * residual;
            rs += redis[i];
        }
        float invr = 1.0f / fmaxf(rs, 1e-6f);
        for (int i = 0; i < 7; ++i) {
            float wi = redis[i] * invr;
            w[i] = wi;
            imp_out[b * 7 + i] = wi;
        }
    }
    __syncthreads();
    float wr[7];
    #pragma unroll
    for (int i = 0; i < 7; ++i) wr[i] = w[i];
    #pragma unroll
    for (int j = 0; j < 4; ++j) {
        int d = tid + j * 256;
        float s = 0.f;
        #pragma unroll
        for (int nn2 = 0; nn2 < 7; ++nn2)
            s += wr[nn2] * upd[(size_t)(b * 7 + nn2) * 1024 + d];
        fused_out[(size_t)b * 1024 + d] = s;
    }
}

__global__ void zero_acc(float* a) { if (threadIdx.x < 4) a[threadIdx.x] = 0.f; }

__global__ __launch_bounds__(256) void physics_k(
    const float* __restrict__ upd, const float* __restrict__ fused,
    float* __restrict__ accums)
{
    const int b = blockIdx.x;
    const int tid = threadIdx.x;
    const int lane = tid & 63, wv = tid >> 6;
    __shared__ float u[7][1024];
    __shared__ float f[1024];
    __shared__ float wred[4][36];
    for (int idx = tid; idx < 7 * 1024; idx += 256)
        u[idx >> 10][idx & 1023] = upd[(size_t)b * 7168 + idx];
    for (int d = tid; d < 1024; d += 256)
        f[d] = fused[(size_t)b * 1024 + d];
    __syncthreads();

    float vals[36];
    #pragma unroll
    for (int i = 0; i < 36; ++i) vals[i] = 0.f;
    for (int d = tid; d < 1024; d += 256) {
        float x[7];
        #pragma unroll
        for (int n = 0; n < 7; ++n) x[n] = u[n][d];
        float fv = f[d];
        int idx = 0;
        #pragma unroll
        for (int n = 0; n < 7; ++n) {
            #pragma unroll
            for (int m = n; m < 7; ++m) vals[idx++] += x[n] * x[m];
        }
        #pragma unroll
        for (int n = 0; n < 7; ++n) vals[28 + n] += x[n] * fv;
        vals[35] += fv * fv;
    }
    #pragma unroll
    for (int i = 0; i < 36; ++i) {
        float s = vals[i];
        #pragma unroll
        for (int off = 32; off > 0; off >>= 1) s += __shfl_down(s, off);
        if (lane == 0) wred[wv][i] = s;
    }
    __syncthreads();
    if (tid == 0) {
        float tv[36];
        for (int i = 0; i < 36; ++i)
            tv[i] = wred[0][i] + wred[1][i] + wred[2][i] + wred[3][i];
        auto didx = [](int n, int m) -> int {
            if (n > m) { int t = n; n = m; m = t; }
            return n * 7 - n * (n - 1) / 2 + (m - n);
        };
        float norms[7];
        for (int n = 0; n < 7; ++n) norms[n] = sqrtf(tv[didx(n, n)]);
        float e = 0.f, nl = 0.f;
        for (int n = 0; n < 7; ++n)
            for (int m = 0; m < 7; ++m) {
                float cos_ = tv[didx(n, m)] / fmaxf(norms[n] * norms[m], 1e-8f);
                float adj = c_adj[n * 7 + m];
                e += (1.0f - cos_) * adj;
                if (adj == 0.0f && n != m) nl += fmaxf(cos_ - 0.35f, 0.0f);
            }
        float fnorm = sqrtf(tv[35]);
        float al = 0.f;
        for (int n = 0; n < 7; ++n) {
            float cosn = tv[28 + n] /
                         (fmaxf(norms[n], 1e-12f) * fmaxf(fnorm, 1e-12f));
            al += 1.0f - cosn;
        }
        atomicAdd(&accums[0], e);
        atomicAdd(&accums[1], nl);
        atomicAdd(&accums[2], al);
    }
}

__global__ void finalize_k(const float* __restrict__ a,
                           float* __restrict__ phys_o,
                           float* __restrict__ align_o)
{
    phys_o[0]  = a[0] / 41.0f + 0.5f * (a[1] / 8.0f);
    align_o[0] = a[2] * (1.0f / 7168.0f);
}

extern "C" void kernel_launch(void* const* d_in, const int* in_sizes, int n_in,
                              void* d_out, int out_size, void* d_ws, size_t ws_size,
                              hipStream_t stream)
{
    const float* nodes = (const float*)d_in[0];
    const float* Wq  = (const float*)d_in[1];
    const float* bq  = (const float*)d_in[2];
    const float* Wk  = (const float*)d_in[3];
    const float* bk  = (const float*)d_in[4];
    const float* Wv  = (const float*)d_in[5];
    const float* bv  = (const float*)d_in[6];
    const float* We1 = (const float*)d_in[7];
    const float* be1 = (const float*)d_in[8];
    const float* We2 = (const float*)d_in[9];
    const float* be2 = (const float*)d_in[10];
    const float* Wu1 = (const float*)d_in[11];
    const float* bu1 = (const float*)d_in[12];
    const float* Wu2 = (const float*)d_in[13];
    const float* bu2 = (const float*)d_in[14];
    const float* Wi1 = (const float*)d_in[15];
    const float* bi1 = (const float*)d_in[16];
    const float* Wi2 = (const float*)d_in[17];
    const float* bi2 = (const float*)d_in[18];

    float* out = (float*)d_out;
    float* fused_o = out;                            // 1,048,576
    float* upd_o   = out + 1048576;                  // 7,340,032
    float* imp_o   = out + 1048576 + 7340032;        // 7,168
    float* attn_o  = imp_o + 7168;                   // 50,176
    float* phys_o  = attn_o + 50176;                 // 1
    float* align_o = phys_o + 1;                     // 1

    const size_t BIG = 7340032;   // B*N*D
    const size_t MEG = 1048576;   // D*D
    char* p = (char*)d_ws;
    unsigned short* nodes_b = (unsigned short*)p; p += BIG * 2;
    unsigned short* qb      = (unsigned short*)p; p += BIG * 2;   // seg 0; reused: h_u
    unsigned short* kb      = (unsigned short*)p; p += BIG * 2;   // seg 1; reused: upd_b
    unsigned short* vb      = (unsigned short*)p; p += BIG * 2;   // seg 2; reused: h_i
    unsigned short* lab     = (unsigned short*)p; p += BIG * 2;   // seg 3; reused: msg
    unsigned short* rbb     = (unsigned short*)p; p += BIG * 2;   // seg 4
    unsigned short* WT_all  = (unsigned short*)p; p += (size_t)6144 * 1024 * 2;
    unsigned short* Wu1T    = (unsigned short*)p; p += 2 * MEG * 2;
    unsigned short* Wu2T    = (unsigned short*)p; p += MEG * 2;
    unsigned short* Wi1T    = (unsigned short*)p; p += 2 * MEG * 2;
    float* bias_all = (float*)p; p += 5120 * 4;
    float* ccf = (float*)p; p += MEG * 4;
    float* il  = (float*)p; p += 7168 * 4;
    float* acc = (float*)p; p += 4 * 4;
    unsigned short* msgb = lab;   // alias: safe (see attn_msg_b)
    unsigned short* hub  = qb;
    unsigned short* updb = kb;
    unsigned short* hib  = vb;

    dim3 blk(256);

    // prep
    cast_f2b<<<dim3(7168), blk, 0, stream>>>(nodes, nodes_b, 7340032);
    tcast_all<<<dim3(32, 64, 9), blk, 0, stream>>>(Wq, Wk, Wv, We1, Wu1, Wu2, Wi1,
                                                   WT_all, Wu1T, Wu2T, Wi1T);
    build_bias<<<dim3(20), blk, 0, stream>>>(bq, bk, bv, bias_all);

    // fused q|k|v|la|rb : N=5120, segmented bf16 out into qb..rbb
    // 256^2 phased kernel: grid 20x28 = 560 blocks, 512 threads
    gemm256<<<dim3(20, 28), dim3(512), 0, stream>>>(
        nodes_b, WT_all, 1024, bias_all, qb, BIG, 1024);

    // cc = nodes[:,-1] @ Wc + be1 (fp32 out), WcT at WT_all row 5120
    gemm64x128<<<dim3(8, 16), blk, 0, stream>>>(
        nodes_b, 1, nullptr, 0, WT_all + (size_t)5120 * 1024, 1024, be1, nullptr,
        ccf, nullptr, 1024, 0);

    // attention + messages (msg overwrites la)
    attn_msg_b<<<dim3(7168), blk, 0, stream>>>(qb, kb, vb, lab, rbb, ccf, We2, be2,
                                               attn_o, msgb);

    // h_u = gelu([nodes|msg] @ Wu1 + bu1)   — 128^2 tile, grid 8x56
    gemm128<<<dim3(8, 56), blk, 0, stream>>>(
        nodes_b, 0, msgb, 0, Wu1T, 2048, bu1, nullptr, nullptr, hub, 0, 2048, 1);
    // updated = h_u @ Wu2 + bu2 + nodes (fp32 out + bf16 copy)
    gemm128<<<dim3(8, 56), blk, 0, stream>>>(
        hub, 0, nullptr, 0, Wu2T, 1024, bu2, nodes, upd_o, updb, 0, 1024, 0);
    // h_i = gelu([updated|ctx] @ Wi1 + bi1)
    gemm128<<<dim3(8, 56), blk, 0, stream>>>(
        updb, 0, updb, 2, Wi1T, 2048, bi1, nullptr, nullptr, hib, 0, 2048, 1);

    // tail
    row_dot_b<<<dim3(7168), blk, 0, stream>>>(hib, Wi2, bi2, il);
    imp_fused_k<<<dim3(1024), blk, 0, stream>>>(il, upd_o, imp_o, fused_o);
    zero_acc<<<1, 64, 0, stream>>>(acc);
    physics_k<<<dim3(1024), blk, 0, stream>>>(upd_o, fused_o, acc);
    finalize_k<<<1, 1, 0, stream>>>(acc, phys_o, align_o);
}

// Round 3
// 581.417 us; speedup vs baseline: 1.0179x; 1.0179x over previous
//
#include <hip/hip_runtime.h>
#include <hip/hip_bf16.h>

// PhysicsGraphFusion: B=1024, N=7, D=1024
// Outputs (flat): fused (B*D), updated (B*N*D), imp (B*N), attn (B*N*N), phys (1), align (1)

typedef __attribute__((ext_vector_type(8))) short bf16x8;
typedef __attribute__((ext_vector_type(4))) float f32x4;

__constant__ float c_adj[49] = {
    1,1,0,0,1,1,1,
    1,1,1,1,1,1,1,
    0,1,1,0,1,0,1,
    0,1,0,1,1,1,1,
    1,1,1,1,1,1,1,
    1,1,0,1,1,1,1,
    1,1,1,1,1,1,1};

__device__ __forceinline__ float gelu_f(float x) {
    return 0.5f * x * (1.0f + erff(x * 0.7071067811865476f));
}
__device__ __forceinline__ float b2f(unsigned short u) {
    unsigned int x = ((unsigned int)u) << 16;
    union { unsigned int i; float f; } c; c.i = x; return c.f;
}
__device__ __forceinline__ unsigned short f2b(float f) {
    __hip_bfloat16 h = __float2bfloat16(f);
    union { __hip_bfloat16 b; unsigned short u; } c; c.b = h; return c.u;
}

__device__ __forceinline__ void gload_lds16(const void* g, void* l) {
    __builtin_amdgcn_global_load_lds(
        (const __attribute__((address_space(1))) unsigned int*)g,
        (__attribute__((address_space(3))) unsigned int*)l, 16, 0, 0);
}

// row mapping: 0: r->r ; 1: r->r*7+6 (ctx rows) ; 2: r->r-r%7+6 (ctx broadcast)
__device__ __forceinline__ int maprow(int r, int mode) {
    if (mode == 1) return r * 7 + 6;
    if (mode == 2) return r - r % 7 + 6;
    return r;
}

// ---------------------------------------------------------------------------
// 128x128-tile double-buffered bf16 MFMA GEMM.
// C[M x N] = epi(Acat[M x K] @ WT^T); WT = W^T [N x K] bf16 row stride ldw.
// Acat cols [0,1024) A1, [1024,2048) A2 (row-mapped via a1Mode/a2Mode).
// Cb segmented: idx = (c>>10)*segStride + r*1024 + (c&1023).
//
// Structure (vs old gemm128): 2-slot LDS ring (32 KB -> ~3 blocks/CU).
// Per K-tile: issue stage(kt+1) FIRST -> ds_read frags(kt) -> 16 MFMA with
// COMPILER-managed lgkmcnt (no inline lgkmcnt: hand-drain serialized
// LDS->MFMA, the R2 regression) -> vmcnt(0) AFTER the MFMA cluster (HBM
// latency hidden under compute, drain ~free) -> one raw s_barrier.
// Race proof: writes to slot (kt+1)&1 are issued in iter kt, strictly after
// the barrier ending iter kt-1, which ended all reads of tile kt-1 (same
// slot). One barrier per K-tile suffices.
// Chunk swizzle (0 bank conflicts measured): LDS chunk = glb chunk ^ ((row>>1)&3).
// XCD swizzle: bijective (all grids used are % 8 == 0).
// ---------------------------------------------------------------------------
__global__ __launch_bounds__(256) void gemm128db(
    const unsigned short* __restrict__ A1, int a1Mode,
    const unsigned short* __restrict__ A2, int a2Mode,
    const unsigned short* __restrict__ WT, int ldw,
    const float* __restrict__ bias,
    const float* __restrict__ resid,
    float* __restrict__ Cf,
    unsigned short* __restrict__ Cb, size_t segStride,
    int K, int act)
{
    __shared__ short As[2][128 * 32];
    __shared__ short Bs[2][128 * 32];
    const int tid = threadIdx.x;
    const int lane = tid & 63;
    const int w = tid >> 6;
    const int wr = (w >> 1) * 64;
    const int wc = (w & 1) * 64;

    // bijective XCD swizzle (nwg % 8 == 0 for all grids used)
    int lin = blockIdx.y * gridDim.x + blockIdx.x;
    const int nwg = gridDim.x * gridDim.y;
    const int cpx = nwg >> 3;
    lin = (lin & 7) * cpx + (lin >> 3);
    const int row0 = (lin / gridDim.x) * 128;
    const int col0 = (lin % gridDim.x) * 128;

    const int fr = lane & 15;
    const int fko = (((lane >> 4) ^ ((fr >> 1) & 3)) << 3);

    const int NTt = K >> 5;   // K-tiles of 32

    auto stage = [&](int ktn) {
        int k0n = ktn * 32;
        const unsigned short* srcA; int mode; int kbase;
        if (k0n < 1024) { srcA = A1; mode = a1Mode; kbase = k0n; }
        else            { srcA = A2; mode = a2Mode; kbase = k0n - 1024; }
        short* Adst = &As[ktn & 1][0];
        short* Bdst = &Bs[ktn & 1][0];
        #pragma unroll
        for (int rnd = 0; rnd < 2; ++rnd) {
            int c = rnd * 256 + tid;
            int m = c >> 2, ch = c & 3;
            int kc = (ch ^ ((m >> 1) & 3)) * 8;   // pre-swizzled global chunk
            int rr = maprow(row0 + m, mode);
            gload_lds16(srcA + (size_t)rr * 1024 + kbase + kc, Adst + c * 8);
        }
        #pragma unroll
        for (int rnd = 0; rnd < 2; ++rnd) {
            int c = rnd * 256 + tid;
            int n = c >> 2, ch = c & 3;
            int kc = (ch ^ ((n >> 1) & 3)) * 8;
            gload_lds16(WT + (size_t)(col0 + n) * ldw + k0n + kc, Bdst + c * 8);
        }
    };

    f32x4 acc[4][4] = {};

    // prologue: stage tile 0, drain, barrier
    stage(0);
    asm volatile("s_waitcnt vmcnt(0)" ::: "memory");
    asm volatile("s_barrier" ::: "memory");

    for (int kt = 0; kt < NTt; ++kt) {
        const short* Ab = &As[kt & 1][0];
        const short* Bb = &Bs[kt & 1][0];

        if (kt + 1 < NTt) stage(kt + 1);   // issue-early: hides HBM latency

        bf16x8 af[4], bfv[4];
        #pragma unroll
        for (int i = 0; i < 4; ++i)
            af[i] = *(const bf16x8*)(Ab + (wr + i * 16 + fr) * 32 + fko);
        #pragma unroll
        for (int j = 0; j < 4; ++j)
            bfv[j] = *(const bf16x8*)(Bb + (wc + j * 16 + fr) * 32 + fko);

        __builtin_amdgcn_s_setprio(1);
        #pragma unroll
        for (int i = 0; i < 4; ++i)
            #pragma unroll
            for (int j = 0; j < 4; ++j)
                acc[i][j] = __builtin_amdgcn_mfma_f32_16x16x32_bf16(
                    af[i], bfv[j], acc[i][j], 0, 0, 0);
        __builtin_amdgcn_s_setprio(0);

        // stage(kt+1) drained here: issued ~1500 cyc ago, wait is ~free
        asm volatile("s_waitcnt vmcnt(0)" ::: "memory");
        asm volatile("s_barrier" ::: "memory");
    }

    const int qrow = (lane >> 4) * 4;
    const int qcol = lane & 15;
    #pragma unroll
    for (int i = 0; i < 4; ++i) {
        int rbase = row0 + wr + i * 16 + qrow;
        #pragma unroll
        for (int j = 0; j < 4; ++j) {
            int c = col0 + wc + j * 16 + qcol;
            float bv = bias ? bias[c] : 0.0f;
            int seg = c >> 10, c0 = c & 1023;
            #pragma unroll
            for (int reg = 0; reg < 4; ++reg) {
                int r = rbase + reg;
                float vv = acc[i][j][reg] + bv;
                if (act) vv = gelu_f(vv);
                if (resid) vv += resid[(size_t)r * 1024 + c];
                if (Cf) Cf[(size_t)r * 1024 + c] = vv;
                if (Cb) Cb[(size_t)seg * segStride + (size_t)r * 1024 + c0] = f2b(vv);
            }
        }
    }
}

// ---------------------------------------------------------------------------
// 64x128-tile bf16 MFMA GEMM (only used for the small ctx GEMM).
// ---------------------------------------------------------------------------
__global__ __launch_bounds__(256) void gemm64x128(
    const unsigned short* __restrict__ A1, int a1Mode,
    const unsigned short* __restrict__ A2, int a2Mode,
    const unsigned short* __restrict__ WT, int ldw,
    const float* __restrict__ bias,
    const float* __restrict__ resid,
    float* __restrict__ Cf,
    unsigned short* __restrict__ Cb,
    int K, int act)
{
    __shared__ short As[64 * 32];
    __shared__ short Bs[128 * 32];
    const int tid = threadIdx.x;
    const int lane = tid & 63;
    const int w = tid >> 6;
    const int wc = w * 32;
    const int row0 = blockIdx.y * 64;
    const int col0 = blockIdx.x * 128;
    const int fr = lane & 15;
    const int fko = (((lane >> 4) ^ ((fr >> 1) & 3)) << 3);

    f32x4 acc[4][2] = {};

    for (int k0 = 0; k0 < K; k0 += 32) {
        const unsigned short* srcA; int mode; int kbase;
        if (k0 < 1024) { srcA = A1; mode = a1Mode; kbase = k0; }
        else           { srcA = A2; mode = a2Mode; kbase = k0 - 1024; }
        {
            int m = tid >> 2, ch = tid & 3;
            int kc = (ch ^ ((m >> 1) & 3)) * 8;
            int rr = maprow(row0 + m, mode);
            gload_lds16(srcA + (size_t)rr * 1024 + kbase + kc, &As[tid * 8]);
        }
        #pragma unroll
        for (int rnd = 0; rnd < 2; ++rnd) {
            int c = rnd * 256 + tid;
            int n = c >> 2, ch = c & 3;
            int kc = (ch ^ ((n >> 1) & 3)) * 8;
            gload_lds16(WT + (size_t)(col0 + n) * ldw + k0 + kc, &Bs[c * 8]);
        }
        __syncthreads();
        bf16x8 af[4], bf_[2];
        #pragma unroll
        for (int i = 0; i < 4; ++i)
            af[i] = *(const bf16x8*)(&As[(i * 16 + fr) * 32 + fko]);
        #pragma unroll
        for (int j = 0; j < 2; ++j)
            bf_[j] = *(const bf16x8*)(&Bs[(wc + j * 16 + fr) * 32 + fko]);
        #pragma unroll
        for (int i = 0; i < 4; ++i)
            #pragma unroll
            for (int j = 0; j < 2; ++j)
                acc[i][j] = __builtin_amdgcn_mfma_f32_16x16x32_bf16(
                    af[i], bf_[j], acc[i][j], 0, 0, 0);
        __syncthreads();
    }

    const int qrow = (lane >> 4) * 4;
    const int qcol = lane & 15;
    #pragma unroll
    for (int i = 0; i < 4; ++i) {
        int rbase = row0 + i * 16 + qrow;
        #pragma unroll
        for (int j = 0; j < 2; ++j) {
            int c = col0 + wc + j * 16 + qcol;
            float bv = bias ? bias[c] : 0.0f;
            #pragma unroll
            for (int reg = 0; reg < 4; ++reg) {
                int r = rbase + reg;
                float vv = acc[i][j][reg] + bv;
                if (act) vv = gelu_f(vv);
                if (resid) vv += resid[(size_t)r * 1024 + c];
                if (Cf) Cf[(size_t)r * 1024 + c] = vv;
                if (Cb) Cb[(size_t)r * 1024 + c] = f2b(vv);
            }
        }
    }
}

// fp32 -> bf16 elementwise cast
__global__ __launch_bounds__(256) void cast_f2b(
    const float* __restrict__ in, unsigned short* __restrict__ out, int n)
{
    int i = (blockIdx.x * 256 + threadIdx.x) * 4;
    if (i >= n) return;
    float4 v = *(const float4*)(in + i);
    ushort4 o;
    o.x = f2b(v.x); o.y = f2b(v.y); o.z = f2b(v.z); o.w = f2b(v.w);
    *(ushort4*)(out + i) = o;
}

// All weight transposes+casts in one dispatch. grid (32, 64, 9).
__global__ __launch_bounds__(256) void tcast_all(
    const float* __restrict__ Wq, const float* __restrict__ Wk,
    const float* __restrict__ Wv, const float* __restrict__ We1,
    const float* __restrict__ Wu1, const float* __restrict__ Wu2,
    const float* __restrict__ Wi1,
    unsigned short* __restrict__ WT_all, unsigned short* __restrict__ Wu1T,
    unsigned short* __restrict__ Wu2T, unsigned short* __restrict__ Wi1T)
{
    const int z = blockIdx.z;
    const float* src; unsigned short* dst; int R;
    switch (z) {
        case 0: src = Wq;            dst = WT_all;               R = 1024; break;
        case 1: src = Wk;            dst = WT_all + 1024 * 1024; R = 1024; break;
        case 2: src = Wv;            dst = WT_all + 2048 * 1024; R = 1024; break;
        case 3: src = We1;           dst = WT_all + 3072 * 1024; R = 1024; break;
        case 4: src = We1 + 1048576; dst = WT_all + 4096 * 1024; R = 1024; break;
        case 5: src = We1 + 2097152; dst = WT_all + 5120 * 1024; R = 1024; break;
        case 6: src = Wu1;           dst = Wu1T;                 R = 2048; break;
        case 7: src = Wu2;           dst = Wu2T;                 R = 1024; break;
        default: src = Wi1;          dst = Wi1T;                 R = 2048; break;
    }
    const int rt = blockIdx.y * 32;
    if (rt >= R) return;
    const int ct = blockIdx.x * 32;
    __shared__ float t[32][33];
    const int tx = threadIdx.x & 31, ty = threadIdx.x >> 5;
    #pragma unroll
    for (int s = 0; s < 4; ++s)
        t[ty + s * 8][tx] = src[(size_t)(rt + ty + s * 8) * 1024 + ct + tx];
    __syncthreads();
    #pragma unroll
    for (int s = 0; s < 4; ++s)
        dst[(size_t)(ct + ty + s * 8) * R + rt + tx] = f2b(t[tx][ty + s * 8]);
}

// bias_all[5120] = [bq | bk | bv | 0 | 0]; also zeroes the accum scratch
__global__ void build_bias(const float* __restrict__ bq,
                           const float* __restrict__ bk,
                           const float* __restrict__ bv,
                           float* __restrict__ bias_all,
                           float* __restrict__ acc)
{
    int i = blockIdx.x * 256 + threadIdx.x;
    if (i < 4) acc[i] = 0.f;
    if (i >= 5120) return;
    int seg = i >> 10, c = i & 1023;
    float v = 0.f;
    if (seg == 0) v = bq[c];
    else if (seg == 1) v = bk[c];
    else if (seg == 2) v = bv[c];
    bias_all[i] = v;
}

// ---------------------------------------------------------------------------
// One block per (b,n): edge MLP + logits + softmax + messages (bf16 in/out)
// msg may alias la (each block reads only its own la row, into regs first).
// ---------------------------------------------------------------------------
__global__ __launch_bounds__(256) void attn_msg_b(
    const unsigned short* __restrict__ q, const unsigned short* __restrict__ k,
    const unsigned short* __restrict__ v,
    const unsigned short* __restrict__ la, const unsigned short* __restrict__ rb,
    const float* __restrict__ cc,
    const float* __restrict__ We2, const float* __restrict__ be2,
    float* __restrict__ attn_out, unsigned short* __restrict__ msg)
{
    const int bn = blockIdx.x;
    const int b = bn / 7, n = bn % 7;
    const int tid = threadIdx.x;
    const int lane = tid & 63, wv = tid >> 6;
    const int d0 = tid * 4;
    __shared__ float red[8];
    __shared__ float sm[7];

    float qv[4], lav[4], ccv[4], wev[4];
    {
        ushort4 q4 = *(const ushort4*)(q + (size_t)bn * 1024 + d0);
        ushort4 l4 = *(const ushort4*)(la + (size_t)bn * 1024 + d0);
        float4 c4 = *(const float4*)(cc + (size_t)b * 1024 + d0);
        float4 w4 = *(const float4*)(We2 + d0);
        qv[0] = b2f(q4.x); qv[1] = b2f(q4.y); qv[2] = b2f(q4.z); qv[3] = b2f(q4.w);
        lav[0] = b2f(l4.x); lav[1] = b2f(l4.y); lav[2] = b2f(l4.z); lav[3] = b2f(l4.w);
        ccv[0] = c4.x; ccv[1] = c4.y; ccv[2] = c4.z; ccv[3] = c4.w;
        wev[0] = w4.x; wev[1] = w4.y; wev[2] = w4.z; wev[3] = w4.w;
    }
    for (int m = 0; m < 7; ++m) {
        ushort4 k4 = *(const ushort4*)(k  + (size_t)(b * 7 + m) * 1024 + d0);
        ushort4 r4 = *(const ushort4*)(rb + (size_t)(b * 7 + m) * 1024 + d0);
        float s1 = qv[0] * b2f(k4.x) + qv[1] * b2f(k4.y)
                 + qv[2] * b2f(k4.z) + qv[3] * b2f(k4.w);
        float s2 = gelu_f(lav[0] + b2f(r4.x) + ccv[0]) * wev[0]
                 + gelu_f(lav[1] + b2f(r4.y) + ccv[1]) * wev[1]
                 + gelu_f(lav[2] + b2f(r4.z) + ccv[2]) * wev[2]
                 + gelu_f(lav[3] + b2f(r4.w) + ccv[3]) * wev[3];
        #pragma unroll
        for (int off = 32; off > 0; off >>= 1) {
            s1 += __shfl_down(s1, off);
            s2 += __shfl_down(s2, off);
        }
        if (lane == 0) { red[wv * 2] = s1; red[wv * 2 + 1] = s2; }
        __syncthreads();
        if (tid == 0) {
            float d1 = red[0] + red[2] + red[4] + red[6];
            float d2 = red[1] + red[3] + red[5] + red[7];
            sm[m] = d1 * (1.0f / 32.0f) + d2 + be2[0]
                  + (c_adj[n * 7 + m] - 1.0f) * 10000.0f;
        }
        __syncthreads();
    }
    if (tid == 0) {
        float mx = sm[0];
        #pragma unroll
        for (int m = 1; m < 7; ++m) mx = fmaxf(mx, sm[m]);
        float e[7], s = 0.f;
        #pragma unroll
        for (int m = 0; m < 7; ++m) { e[m] = expf(sm[m] - mx); s += e[m]; }
        float inv = 1.0f / s;
        #pragma unroll
        for (int m = 0; m < 7; ++m) {
            float wgt = e[m] * inv;
            sm[m] = wgt;
            attn_out[(size_t)bn * 7 + m] = wgt;
        }
    }
    __syncthreads();
    float wr_[7];
    #pragma unroll
    for (int m = 0; m < 7; ++m) wr_[m] = sm[m];
    float s0 = 0.f, s1 = 0.f, s2 = 0.f, s3 = 0.f;
    #pragma unroll
    for (int m = 0; m < 7; ++m) {
        ushort4 v4 = *(const ushort4*)(v + (size_t)(b * 7 + m) * 1024 + d0);
        s0 += wr_[m] * b2f(v4.x); s1 += wr_[m] * b2f(v4.y);
        s2 += wr_[m] * b2f(v4.z); s3 += wr_[m] * b2f(v4.w);
    }
    ushort4 o;
    o.x = f2b(s0); o.y = f2b(s1); o.z = f2b(s2); o.w = f2b(s3);
    *(ushort4*)(msg + (size_t)bn * 1024 + d0) = o;
}

// imp_logits[r] = dot(H[r,:], w2) + b2[0]   (H bf16)
__global__ __launch_bounds__(256) void row_dot_b(
    const unsigned short* __restrict__ H, const float* __restrict__ w2,
    const float* __restrict__ b2, float* __restrict__ out)
{
    const int r = blockIdx.x;
    const int tid = threadIdx.x;
    const int lane = tid & 63, wv = tid >> 6;
    __shared__ float red[4];
    const int d0 = tid * 4;
    ushort4 h4 = *(const ushort4*)(H + (size_t)r * 1024 + d0);
    float4 w4 = *(const float4*)(w2 + d0);
    float s = b2f(h4.x) * w4.x + b2f(h4.y) * w4.y
            + b2f(h4.z) * w4.z + b2f(h4.w) * w4.w;
    #pragma unroll
    for (int off = 32; off > 0; off >>= 1) s += __shfl_down(s, off);
    if (lane == 0) red[wv] = s;
    __syncthreads();
    if (tid == 0) out[r] = red[0] + red[1] + red[2] + red[3] + b2[0];
}

// per-b: softmax over N, cap/redistribute, imp; fused = sum_n imp*updated
__global__ __launch_bounds__(256) void imp_fused_k(
    const float* __restrict__ logits, const float* __restrict__ upd,
    float* __restrict__ imp_out, float* __restrict__ fused_out)
{
    const int b = blockIdx.x;
    const int tid = threadIdx.x;
    __shared__ float w[7];
    if (tid == 0) {
        float l[7], e[7];
        float mx = -1e30f;
        for (int i = 0; i < 7; ++i) { l[i] = logits[b * 7 + i]; mx = fmaxf(mx, l[i]); }
        float s = 0.f;
        for (int i = 0; i < 7; ++i) { e[i] = expf(l[i] - mx); s += e[i]; }
        float inv = 1.0f / s;
        float imp[7];
        for (int i = 0; i < 7; ++i) imp[i] = e[i] * inv;
        const float cap[7] = {1.f, 1.f, 1.f, 0.26f, 1.f, 1.f, 0.24f};
        const float fr[7]  = {1.f, 1.f, 1.f, 0.f,   1.f, 1.f, 0.f};
        float capped[7], capsum = 0.f, fmass = 0.f;
        for (int i = 0; i < 7; ++i) {
            capped[i] = fminf(imp[i], cap[i]);
            capsum += capped[i];
            fmass += imp[i] * fr[i];
        }
        float residual = fmaxf(1.0f - capsum, 0.0f);
        float redis[7], rs = 0.f;
        for (int i = 0; i < 7; ++i) {
            float fs = (fmass > 1e-6f) ? imp[i] * fr[i] / fmaxf(fmass, 1e-6f)
                                       : fr[i] * 0.2f;
            redis[i] = capped[i] + fs * residual;
            rs += redis[i];
        }
        float invr = 1.0f / fmaxf(rs, 1e-6f);
        for (int i = 0; i < 7; ++i) {
            float wi = redis[i] * invr;
            w[i] = wi;
            imp_out[b * 7 + i] = wi;
        }
    }
    __syncthreads();
    float wr[7];
    #pragma unroll
    for (int i = 0; i < 7; ++i) wr[i] = w[i];
    #pragma unroll
    for (int j = 0; j < 4; ++j) {
        int d = tid + j * 256;
        float s = 0.f;
        #pragma unroll
        for (int nn2 = 0; nn2 < 7; ++nn2)
            s += wr[nn2] * upd[(size_t)(b * 7 + nn2) * 1024 + d];
        fused_out[(size_t)b * 1024 + d] = s;
    }
}

__global__ __launch_bounds__(256) void physics_k(
    const float* __restrict__ upd, const float* __restrict__ fused,
    float* __restrict__ accums)
{
    const int b = blockIdx.x;
    const int tid = threadIdx.x;
    const int lane = tid & 63, wv = tid >> 6;
    __shared__ float u[7][1024];
    __shared__ float f[1024];
    __shared__ float wred[4][36];
    for (int idx = tid; idx < 7 * 1024; idx += 256)
        u[idx >> 10][idx & 1023] = upd[(size_t)b * 7168 + idx];
    for (int d = tid; d < 1024; d += 256)
        f[d] = fused[(size_t)b * 1024 + d];
    __syncthreads();

    float vals[36];
    #pragma unroll
    for (int i = 0; i < 36; ++i) vals[i] = 0.f;
    for (int d = tid; d < 1024; d += 256) {
        float x[7];
        #pragma unroll
        for (int n = 0; n < 7; ++n) x[n] = u[n][d];
        float fv = f[d];
        int idx = 0;
        #pragma unroll
        for (int n = 0; n < 7; ++n) {
            #pragma unroll
            for (int m = n; m < 7; ++m) vals[idx++] += x[n] * x[m];
        }
        #pragma unroll
        for (int n = 0; n < 7; ++n) vals[28 + n] += x[n] * fv;
        vals[35] += fv * fv;
    }
    #pragma unroll
    for (int i = 0; i < 36; ++i) {
        float s = vals[i];
        #pragma unroll
        for (int off = 32; off > 0; off >>= 1) s += __shfl_down(s, off);
        if (lane == 0) wred[wv][i] = s;
    }
    __syncthreads();
    if (tid == 0) {
        float tv[36];
        for (int i = 0; i < 36; ++i)
            tv[i] = wred[0][i] + wred[1][i] + wred[2][i] + wred[3][i];
        auto didx = [](int n, int m) -> int {
            if (n > m) { int t = n; n = m; m = t; }
            return n * 7 - n * (n - 1) / 2 + (m - n);
        };
        float norms[7];
        for (int n = 0; n < 7; ++n) norms[n] = sqrtf(tv[didx(n, n)]);
        float e = 0.f, nl = 0.f;
        for (int n = 0; n < 7; ++n)
            for (int m = 0; m < 7; ++m) {
                float cos_ = tv[didx(n, m)] / fmaxf(norms[n] * norms[m], 1e-8f);
                float adj = c_adj[n * 7 + m];
                e += (1.0f - cos_) * adj;
                if (adj == 0.0f && n != m) nl += fmaxf(cos_ - 0.35f, 0.0f);
            }
        float fnorm = sqrtf(tv[35]);
        float al = 0.f;
        for (int n = 0; n < 7; ++n) {
            float cosn = tv[28 + n] /
                         (fmaxf(norms[n], 1e-12f) * fmaxf(fnorm, 1e-12f));
            al += 1.0f - cosn;
        }
        atomicAdd(&accums[0], e);
        atomicAdd(&accums[1], nl);
        atomicAdd(&accums[2], al);
    }
}

__global__ void finalize_k(const float* __restrict__ a,
                           float* __restrict__ phys_o,
                           float* __restrict__ align_o)
{
    phys_o[0]  = a[0] / 41.0f + 0.5f * (a[1] / 8.0f);
    align_o[0] = a[2] * (1.0f / 7168.0f);
}

extern "C" void kernel_launch(void* const* d_in, const int* in_sizes, int n_in,
                              void* d_out, int out_size, void* d_ws, size_t ws_size,
                              hipStream_t stream)
{
    const float* nodes = (const float*)d_in[0];
    const float* Wq  = (const float*)d_in[1];
    const float* bq  = (const float*)d_in[2];
    const float* Wk  = (const float*)d_in[3];
    const float* bk  = (const float*)d_in[4];
    const float* Wv  = (const float*)d_in[5];
    const float* bv  = (const float*)d_in[6];
    const float* We1 = (const float*)d_in[7];
    const float* be1 = (const float*)d_in[8];
    const float* We2 = (const float*)d_in[9];
    const float* be2 = (const float*)d_in[10];
    const float* Wu1 = (const float*)d_in[11];
    const float* bu1 = (const float*)d_in[12];
    const float* Wu2 = (const float*)d_in[13];
    const float* bu2 = (const float*)d_in[14];
    const float* Wi1 = (const float*)d_in[15];
    const float* bi1 = (const float*)d_in[16];
    const float* Wi2 = (const float*)d_in[17];
    const float* bi2 = (const float*)d_in[18];

    float* out = (float*)d_out;
    float* fused_o = out;                            // 1,048,576
    float* upd_o   = out + 1048576;                  // 7,340,032
    float* imp_o   = out + 1048576 + 7340032;        // 7,168
    float* attn_o  = imp_o + 7168;                   // 50,176
    float* phys_o  = attn_o + 50176;                 // 1
    float* align_o = phys_o + 1;                     // 1

    const size_t BIG = 7340032;   // B*N*D
    const size_t MEG = 1048576;   // D*D
    char* p = (char*)d_ws;
    unsigned short* nodes_b = (unsigned short*)p; p += BIG * 2;
    unsigned short* qb      = (unsigned short*)p; p += BIG * 2;   // seg 0; reused: h_u
    unsigned short* kb      = (unsigned short*)p; p += BIG * 2;   // seg 1; reused: upd_b
    unsigned short* vb      = (unsigned short*)p; p += BIG * 2;   // seg 2; reused: h_i
    unsigned short* lab     = (unsigned short*)p; p += BIG * 2;   // seg 3; reused: msg
    unsigned short* rbb     = (unsigned short*)p; p += BIG * 2;   // seg 4
    unsigned short* WT_all  = (unsigned short*)p; p += (size_t)6144 * 1024 * 2;
    unsigned short* Wu1T    = (unsigned short*)p; p += 2 * MEG * 2;
    unsigned short* Wu2T    = (unsigned short*)p; p += MEG * 2;
    unsigned short* Wi1T    = (unsigned short*)p; p += 2 * MEG * 2;
    float* bias_all = (float*)p; p += 5120 * 4;
    float* ccf = (float*)p; p += MEG * 4;
    float* il  = (float*)p; p += 7168 * 4;
    float* acc = (float*)p; p += 4 * 4;
    unsigned short* msgb = lab;   // alias: safe (see attn_msg_b)
    unsigned short* hub  = qb;
    unsigned short* updb = kb;
    unsigned short* hib  = vb;

    dim3 blk(256);

    // prep
    cast_f2b<<<dim3(7168), blk, 0, stream>>>(nodes, nodes_b, 7340032);
    tcast_all<<<dim3(32, 64, 9), blk, 0, stream>>>(Wq, Wk, Wv, We1, Wu1, Wu2, Wi1,
                                                   WT_all, Wu1T, Wu2T, Wi1T);
    build_bias<<<dim3(20), blk, 0, stream>>>(bq, bk, bv, bias_all, acc);

    // fused q|k|v|la|rb : N=5120, segmented bf16 out into qb..rbb
    // grid 40x20... (cols, rows) = (5120/128, 7168/128) = (40, 56) -> 2240 blocks
    gemm128db<<<dim3(40, 56), blk, 0, stream>>>(
        nodes_b, 0, nullptr, 0, WT_all, 1024, bias_all, nullptr,
        nullptr, qb, BIG, 1024, 0);

    // cc = nodes[:,-1] @ Wc + be1 (fp32 out), WcT at WT_all row 5120
    gemm64x128<<<dim3(8, 16), blk, 0, stream>>>(
        nodes_b, 1, nullptr, 0, WT_all + (size_t)5120 * 1024, 1024, be1, nullptr,
        ccf, nullptr, 1024, 0);

    // attention + messages (msg overwrites la)
    attn_msg_b<<<dim3(7168), blk, 0, stream>>>(qb, kb, vb, lab, rbb, ccf, We2, be2,
                                               attn_o, msgb);

    // h_u = gelu([nodes|msg] @ Wu1 + bu1)
    gemm128db<<<dim3(8, 56), blk, 0, stream>>>(
        nodes_b, 0, msgb, 0, Wu1T, 2048, bu1, nullptr, nullptr, hub, 0, 2048, 1);
    // updated = h_u @ Wu2 + bu2 + nodes (fp32 out + bf16 copy)
    gemm128db<<<dim3(8, 56), blk, 0, stream>>>(
        hub, 0, nullptr, 0, Wu2T, 1024, bu2, nodes, upd_o, updb, 0, 1024, 0);
    // h_i = gelu([updated|ctx] @ Wi1 + bi1)
    gemm128db<<<dim3(8, 56), blk, 0, stream>>>(
        updb, 0, updb, 2, Wi1T, 2048, bi1, nullptr, nullptr, hib, 0, 2048, 1);

    // tail
    row_dot_b<<<dim3(7168), blk, 0, stream>>>(hib, Wi2, bi2, il);
    imp_fused_k<<<dim3(1024), blk, 0, stream>>>(il, upd_o, imp_o, fused_o);
    physics_k<<<dim3(1024), blk, 0, stream>>>(upd_o, fused_o, acc);
    finalize_k<<<1, 1, 0, stream>>>(acc, phys_o, align_o);
}

// Round 4
// 535.161 us; speedup vs baseline: 1.1059x; 1.0864x over previous
//
#include <hip/hip_runtime.h>
#include <hip/hip_bf16.h>

// PhysicsGraphFusion: B=1024, N=7, D=1024
// Outputs (flat): fused (B*D), updated (B*N*D), imp (B*N), attn (B*N*N), phys (1), align (1)

typedef __attribute__((ext_vector_type(8))) short bf16x8;
typedef __attribute__((ext_vector_type(4))) float f32x4;

__constant__ float c_adj[49] = {
    1,1,0,0,1,1,1,
    1,1,1,1,1,1,1,
    0,1,1,0,1,0,1,
    0,1,0,1,1,1,1,
    1,1,1,1,1,1,1,
    1,1,0,1,1,1,1,
    1,1,1,1,1,1,1};

// gelu via Abramowitz-Stegun 7.1.26 erf (|err| < 1.5e-7, ~12 VALU ops vs
// libm erff's ~25+). Error negligible vs bf16 rounding (absmax budget 3e-2).
__device__ __forceinline__ float gelu_f(float x) {
    float z = fabsf(x) * 0.70710678118654752f;
    float t = 1.0f / (1.0f + 0.3275911f * z);
    float poly = ((((1.061405429f * t - 1.453152027f) * t + 1.421413741f) * t
                  - 0.284496736f) * t + 0.254829592f) * t;
    float e = __expf(-z * z);
    float erf_abs = 1.0f - poly * e;
    float erf = copysignf(erf_abs, x);
    return 0.5f * x * (1.0f + erf);
}
__device__ __forceinline__ float b2f(unsigned short u) {
    unsigned int x = ((unsigned int)u) << 16;
    union { unsigned int i; float f; } c; c.i = x; return c.f;
}
__device__ __forceinline__ unsigned short f2b(float f) {
    __hip_bfloat16 h = __float2bfloat16(f);
    union { __hip_bfloat16 b; unsigned short u; } c; c.b = h; return c.u;
}

__device__ __forceinline__ void gload_lds16(const void* g, void* l) {
    __builtin_amdgcn_global_load_lds(
        (const __attribute__((address_space(1))) unsigned int*)g,
        (__attribute__((address_space(3))) unsigned int*)l, 16, 0, 0);
}

// row mapping: 0: r->r ; 1: r->r*7+6 (ctx rows) ; 2: r->r-r%7+6 (ctx broadcast)
__device__ __forceinline__ int maprow(int r, int mode) {
    if (mode == 1) return r * 7 + 6;
    if (mode == 2) return r - r % 7 + 6;
    return r;
}

// ---------------------------------------------------------------------------
// 128x128-tile, 8-wave (512-thread) bf16 MFMA GEMM, 3-slot LDS ring,
// counted vmcnt.
//
// WHY 8 waves: the 4-wave/64x64-per-wave variant needs 76 VGPR + 64 AGPR
// = ~140 unified regs -> occupancy caps at 8 waves/CU (2 blocks), measured
// 31% / MfmaUtil 26% across three schedule variants. 64x32-per-wave needs
// acc=32 AGPR + ~60-70 VGPR <= 128 -> 16 waves/CU (4 waves/SIMD), doubling
// latency-hiding capacity. __launch_bounds__(512,4) pins regs <= 128.
//
// Ring: 3 slots x (128x32) per operand = 48 KB LDS. Iter kt: issue
// stage(kt+2) -> ds_read frags(kt) -> 8 MFMA (compiler-managed lgkmcnt) ->
// vmcnt(2) [tail vmcnt(0)] -> s_barrier. Race proof: iter kt reads slot
// kt%3 and writes slot (kt+2)%3 (distinct mod 3); the slot written at kt
// was last read at iter kt-1 (tile kt-1: (kt-1)%3 == (kt+2)%3), which all
// waves left at the barrier ending iter kt-1. Counted vmcnt(2) leaves tile
// kt+2's 2 per-wave loads in flight across the barrier (T4).
// Chunk swizzle (0 conflicts measured): LDS chunk = glb chunk ^ ((row>>1)&3).
// XCD swizzle: bijective (all grids % 8 == 0).
// ---------------------------------------------------------------------------
__global__ __launch_bounds__(512, 4) void gemm128x8w(
    const unsigned short* __restrict__ A1, int a1Mode,
    const unsigned short* __restrict__ A2, int a2Mode,
    const unsigned short* __restrict__ WT, int ldw,
    const float* __restrict__ bias,
    const float* __restrict__ resid,
    float* __restrict__ Cf,
    unsigned short* __restrict__ Cb, size_t segStride,
    int K, int act)
{
    __shared__ short As[3][128 * 32];
    __shared__ short Bs[3][128 * 32];
    const int tid = threadIdx.x;
    const int lane = tid & 63;
    const int w = tid >> 6;            // 8 waves
    const int wr = (w >> 2) * 64;      // 0,64
    const int wc = (w & 3) * 32;       // 0,32,64,96

    // bijective XCD swizzle (nwg % 8 == 0 for all grids used)
    int lin = blockIdx.y * gridDim.x + blockIdx.x;
    const int nwg = gridDim.x * gridDim.y;
    const int cpx = nwg >> 3;
    lin = (lin & 7) * cpx + (lin >> 3);
    const int row0 = (lin / gridDim.x) * 128;
    const int col0 = (lin % gridDim.x) * 128;

    const int fr = lane & 15;
    const int fko = (((lane >> 4) ^ ((fr >> 1) & 3)) << 3);

    // staging: 512 threads x 16B cover one 128x32 operand tile per round.
    const int sm_ = tid >> 2, sch = tid & 3;
    const int skc = (sch ^ ((sm_ >> 1) & 3)) * 8;   // pre-swizzled glb chunk
    const int ldsoff = tid * 8;                     // linear LDS dest

    const int NTt = K >> 5;

    auto stage = [&](int ktn) {
        int k0n = ktn * 32;
        const unsigned short* srcA; int mode; int kbase;
        if (k0n < 1024) { srcA = A1; mode = a1Mode; kbase = k0n; }
        else            { srcA = A2; mode = a2Mode; kbase = k0n - 1024; }
        int slot = ktn % 3;
        int rr = maprow(row0 + sm_, mode);
        gload_lds16(srcA + (size_t)rr * 1024 + kbase + skc, &As[slot][ldsoff]);
        gload_lds16(WT + (size_t)(col0 + sm_) * ldw + k0n + skc, &Bs[slot][ldsoff]);
    };

    f32x4 acc[4][2] = {};

    // prologue: stage tiles 0,1; wait tile 0 (vmcnt(2): tile 1 stays in flight)
    stage(0);
    if (NTt > 1) stage(1);
    asm volatile("s_waitcnt vmcnt(2)" ::: "memory");
    asm volatile("s_barrier" ::: "memory");

    for (int kt = 0; kt < NTt; ++kt) {
        const short* Ab = &As[kt % 3][0];
        const short* Bb = &Bs[kt % 3][0];

        if (kt + 2 < NTt) stage(kt + 2);   // 2-tile lookahead

        bf16x8 af[4], bfv[2];
        #pragma unroll
        for (int i = 0; i < 4; ++i)
            af[i] = *(const bf16x8*)(Ab + (wr + i * 16 + fr) * 32 + fko);
        #pragma unroll
        for (int j = 0; j < 2; ++j)
            bfv[j] = *(const bf16x8*)(Bb + (wc + j * 16 + fr) * 32 + fko);

        __builtin_amdgcn_s_setprio(1);
        #pragma unroll
        for (int i = 0; i < 4; ++i)
            #pragma unroll
            for (int j = 0; j < 2; ++j)
                acc[i][j] = __builtin_amdgcn_mfma_f32_16x16x32_bf16(
                    af[i], bfv[j], acc[i][j], 0, 0, 0);
        __builtin_amdgcn_s_setprio(0);

        // tile kt+1 must be landed; tile kt+2 stays in flight (counted)
        if (kt < NTt - 2) asm volatile("s_waitcnt vmcnt(2)" ::: "memory");
        else              asm volatile("s_waitcnt vmcnt(0)" ::: "memory");
        asm volatile("s_barrier" ::: "memory");
    }

    const int qrow = (lane >> 4) * 4;
    const int qcol = lane & 15;
    #pragma unroll
    for (int i = 0; i < 4; ++i) {
        int rbase = row0 + wr + i * 16 + qrow;
        #pragma unroll
        for (int j = 0; j < 2; ++j) {
            int c = col0 + wc + j * 16 + qcol;
            float bv = bias ? bias[c] : 0.0f;
            int seg = c >> 10, c0 = c & 1023;
            #pragma unroll
            for (int reg = 0; reg < 4; ++reg) {
                int r = rbase + reg;
                float vv = acc[i][j][reg] + bv;
                if (act) vv = gelu_f(vv);
                if (resid) vv += resid[(size_t)r * 1024 + c];
                if (Cf) Cf[(size_t)r * 1024 + c] = vv;
                if (Cb) Cb[(size_t)seg * segStride + (size_t)r * 1024 + c0] = f2b(vv);
            }
        }
    }
}

// ---------------------------------------------------------------------------
// 64x128-tile bf16 MFMA GEMM (only used for the small ctx GEMM).
// ---------------------------------------------------------------------------
__global__ __launch_bounds__(256) void gemm64x128(
    const unsigned short* __restrict__ A1, int a1Mode,
    const unsigned short* __restrict__ A2, int a2Mode,
    const unsigned short* __restrict__ WT, int ldw,
    const float* __restrict__ bias,
    const float* __restrict__ resid,
    float* __restrict__ Cf,
    unsigned short* __restrict__ Cb,
    int K, int act)
{
    __shared__ short As[64 * 32];
    __shared__ short Bs[128 * 32];
    const int tid = threadIdx.x;
    const int lane = tid & 63;
    const int w = tid >> 6;
    const int wc = w * 32;
    const int row0 = blockIdx.y * 64;
    const int col0 = blockIdx.x * 128;
    const int fr = lane & 15;
    const int fko = (((lane >> 4) ^ ((fr >> 1) & 3)) << 3);

    f32x4 acc[4][2] = {};

    for (int k0 = 0; k0 < K; k0 += 32) {
        const unsigned short* srcA; int mode; int kbase;
        if (k0 < 1024) { srcA = A1; mode = a1Mode; kbase = k0; }
        else           { srcA = A2; mode = a2Mode; kbase = k0 - 1024; }
        {
            int m = tid >> 2, ch = tid & 3;
            int kc = (ch ^ ((m >> 1) & 3)) * 8;
            int rr = maprow(row0 + m, mode);
            gload_lds16(srcA + (size_t)rr * 1024 + kbase + kc, &As[tid * 8]);
        }
        #pragma unroll
        for (int rnd = 0; rnd < 2; ++rnd) {
            int c = rnd * 256 + tid;
            int n = c >> 2, ch = c & 3;
            int kc = (ch ^ ((n >> 1) & 3)) * 8;
            gload_lds16(WT + (size_t)(col0 + n) * ldw + k0 + kc, &Bs[c * 8]);
        }
        __syncthreads();
        bf16x8 af[4], bf_[2];
        #pragma unroll
        for (int i = 0; i < 4; ++i)
            af[i] = *(const bf16x8*)(&As[(i * 16 + fr) * 32 + fko]);
        #pragma unroll
        for (int j = 0; j < 2; ++j)
            bf_[j] = *(const bf16x8*)(&Bs[(wc + j * 16 + fr) * 32 + fko]);
        #pragma unroll
        for (int i = 0; i < 4; ++i)
            #pragma unroll
            for (int j = 0; j < 2; ++j)
                acc[i][j] = __builtin_amdgcn_mfma_f32_16x16x32_bf16(
                    af[i], bf_[j], acc[i][j], 0, 0, 0);
        __syncthreads();
    }

    const int qrow = (lane >> 4) * 4;
    const int qcol = lane & 15;
    #pragma unroll
    for (int i = 0; i < 4; ++i) {
        int rbase = row0 + i * 16 + qrow;
        #pragma unroll
        for (int j = 0; j < 2; ++j) {
            int c = col0 + wc + j * 16 + qcol;
            float bv = bias ? bias[c] : 0.0f;
            #pragma unroll
            for (int reg = 0; reg < 4; ++reg) {
                int r = rbase + reg;
                float vv = acc[i][j][reg] + bv;
                if (act) vv = gelu_f(vv);
                if (resid) vv += resid[(size_t)r * 1024 + c];
                if (Cf) Cf[(size_t)r * 1024 + c] = vv;
                if (Cb) Cb[(size_t)r * 1024 + c] = f2b(vv);
            }
        }
    }
}

// fp32 -> bf16 elementwise cast
__global__ __launch_bounds__(256) void cast_f2b(
    const float* __restrict__ in, unsigned short* __restrict__ out, int n)
{
    int i = (blockIdx.x * 256 + threadIdx.x) * 4;
    if (i >= n) return;
    float4 v = *(const float4*)(in + i);
    ushort4 o;
    o.x = f2b(v.x); o.y = f2b(v.y); o.z = f2b(v.z); o.w = f2b(v.w);
    *(ushort4*)(out + i) = o;
}

// All weight transposes+casts in one dispatch. grid (32, 64, 9).
__global__ __launch_bounds__(256) void tcast_all(
    const float* __restrict__ Wq, const float* __restrict__ Wk,
    const float* __restrict__ Wv, const float* __restrict__ We1,
    const float* __restrict__ Wu1, const float* __restrict__ Wu2,
    const float* __restrict__ Wi1,
    unsigned short* __restrict__ WT_all, unsigned short* __restrict__ Wu1T,
    unsigned short* __restrict__ Wu2T, unsigned short* __restrict__ Wi1T)
{
    const int z = blockIdx.z;
    const float* src; unsigned short* dst; int R;
    switch (z) {
        case 0: src = Wq;            dst = WT_all;               R = 1024; break;
        case 1: src = Wk;            dst = WT_all + 1024 * 1024; R = 1024; break;
        case 2: src = Wv;            dst = WT_all + 2048 * 1024; R = 1024; break;
        case 3: src = We1;           dst = WT_all + 3072 * 1024; R = 1024; break;
        case 4: src = We1 + 1048576; dst = WT_all + 4096 * 1024; R = 1024; break;
        case 5: src = We1 + 2097152; dst = WT_all + 5120 * 1024; R = 1024; break;
        case 6: src = Wu1;           dst = Wu1T;                 R = 2048; break;
        case 7: src = Wu2;           dst = Wu2T;                 R = 1024; break;
        default: src = Wi1;          dst = Wi1T;                 R = 2048; break;
    }
    const int rt = blockIdx.y * 32;
    if (rt >= R) return;
    const int ct = blockIdx.x * 32;
    __shared__ float t[32][33];
    const int tx = threadIdx.x & 31, ty = threadIdx.x >> 5;
    #pragma unroll
    for (int s = 0; s < 4; ++s)
        t[ty + s * 8][tx] = src[(size_t)(rt + ty + s * 8) * 1024 + ct + tx];
    __syncthreads();
    #pragma unroll
    for (int s = 0; s < 4; ++s)
        dst[(size_t)(ct + ty + s * 8) * R + rt + tx] = f2b(t[tx][ty + s * 8]);
}

// bias_all[5120] = [bq | bk | bv | 0 | 0]; also zeroes the accum scratch
__global__ void build_bias(const float* __restrict__ bq,
                           const float* __restrict__ bk,
                           const float* __restrict__ bv,
                           float* __restrict__ bias_all,
                           float* __restrict__ acc)
{
    int i = blockIdx.x * 256 + threadIdx.x;
    if (i < 4) acc[i] = 0.f;
    if (i >= 5120) return;
    int seg = i >> 10, c = i & 1023;
    float v = 0.f;
    if (seg == 0) v = bq[c];
    else if (seg == 1) v = bk[c];
    else if (seg == 2) v = bv[c];
    bias_all[i] = v;
}

// ---------------------------------------------------------------------------
// One block per (b,n): edge MLP + logits + softmax + messages (bf16 in/out).
// v2: all 7 m-partials accumulated in registers first -> ONE reduction phase
// (2 barriers instead of 14); cc folded into la once; fast gelu.
// msg may alias la (each block reads only its own la row, into regs first).
// ---------------------------------------------------------------------------
__global__ __launch_bounds__(256) void attn_msg_b(
    const unsigned short* __restrict__ q, const unsigned short* __restrict__ k,
    const unsigned short* __restrict__ v,
    const unsigned short* __restrict__ la, const unsigned short* __restrict__ rb,
    const float* __restrict__ cc,
    const float* __restrict__ We2, const float* __restrict__ be2,
    float* __restrict__ attn_out, unsigned short* __restrict__ msg)
{
    const int bn = blockIdx.x;
    const int b = bn / 7, n = bn % 7;
    const int tid = threadIdx.x;
    const int lane = tid & 63, wv = tid >> 6;
    const int d0 = tid * 4;
    __shared__ float red[4][14];
    __shared__ float sm[7];

    float qv[4], lav[4], wev[4];
    {
        ushort4 q4 = *(const ushort4*)(q + (size_t)bn * 1024 + d0);
        ushort4 l4 = *(const ushort4*)(la + (size_t)bn * 1024 + d0);
        float4 c4 = *(const float4*)(cc + (size_t)b * 1024 + d0);
        float4 w4 = *(const float4*)(We2 + d0);
        qv[0] = b2f(q4.x); qv[1] = b2f(q4.y); qv[2] = b2f(q4.z); qv[3] = b2f(q4.w);
        // fold cc (includes be1) into la once
        lav[0] = b2f(l4.x) + c4.x; lav[1] = b2f(l4.y) + c4.y;
        lav[2] = b2f(l4.z) + c4.z; lav[3] = b2f(l4.w) + c4.w;
        wev[0] = w4.x; wev[1] = w4.y; wev[2] = w4.z; wev[3] = w4.w;
    }

    float s1a[7], s2a[7];
    #pragma unroll
    for (int m = 0; m < 7; ++m) {
        ushort4 k4 = *(const ushort4*)(k  + (size_t)(b * 7 + m) * 1024 + d0);
        ushort4 r4 = *(const ushort4*)(rb + (size_t)(b * 7 + m) * 1024 + d0);
        s1a[m] = qv[0] * b2f(k4.x) + qv[1] * b2f(k4.y)
               + qv[2] * b2f(k4.z) + qv[3] * b2f(k4.w);
        s2a[m] = gelu_f(lav[0] + b2f(r4.x)) * wev[0]
               + gelu_f(lav[1] + b2f(r4.y)) * wev[1]
               + gelu_f(lav[2] + b2f(r4.z)) * wev[2]
               + gelu_f(lav[3] + b2f(r4.w)) * wev[3];
    }
    #pragma unroll
    for (int m = 0; m < 7; ++m) {
        float x1 = s1a[m], x2 = s2a[m];
        #pragma unroll
        for (int off = 32; off > 0; off >>= 1) {
            x1 += __shfl_down(x1, off);
            x2 += __shfl_down(x2, off);
        }
        if (lane == 0) { red[wv][m] = x1; red[wv][7 + m] = x2; }
    }
    __syncthreads();
    if (tid == 0) {
        float l[7];
        #pragma unroll
        for (int m = 0; m < 7; ++m) {
            float d1 = red[0][m] + red[1][m] + red[2][m] + red[3][m];
            float d2 = red[0][7 + m] + red[1][7 + m] + red[2][7 + m] + red[3][7 + m];
            l[m] = d1 * (1.0f / 32.0f) + d2 + be2[0]
                 + (c_adj[n * 7 + m] - 1.0f) * 10000.0f;
        }
        float mx = l[0];
        #pragma unroll
        for (int m = 1; m < 7; ++m) mx = fmaxf(mx, l[m]);
        float e[7], s = 0.f;
        #pragma unroll
        for (int m = 0; m < 7; ++m) { e[m] = __expf(l[m] - mx); s += e[m]; }
        float inv = 1.0f / s;
        #pragma unroll
        for (int m = 0; m < 7; ++m) {
            float wgt = e[m] * inv;
            sm[m] = wgt;
            attn_out[(size_t)bn * 7 + m] = wgt;
        }
    }
    __syncthreads();
    float wr_[7];
    #pragma unroll
    for (int m = 0; m < 7; ++m) wr_[m] = sm[m];
    float s0 = 0.f, s1 = 0.f, s2 = 0.f, s3 = 0.f;
    #pragma unroll
    for (int m = 0; m < 7; ++m) {
        ushort4 v4 = *(const ushort4*)(v + (size_t)(b * 7 + m) * 1024 + d0);
        s0 += wr_[m] * b2f(v4.x); s1 += wr_[m] * b2f(v4.y);
        s2 += wr_[m] * b2f(v4.z); s3 += wr_[m] * b2f(v4.w);
    }
    ushort4 o;
    o.x = f2b(s0); o.y = f2b(s1); o.z = f2b(s2); o.w = f2b(s3);
    *(ushort4*)(msg + (size_t)bn * 1024 + d0) = o;
}

// imp_logits[r] = dot(H[r,:], w2) + b2[0]   (H bf16)
__global__ __launch_bounds__(256) void row_dot_b(
    const unsigned short* __restrict__ H, const float* __restrict__ w2,
    const float* __restrict__ b2, float* __restrict__ out)
{
    const int r = blockIdx.x;
    const int tid = threadIdx.x;
    const int lane = tid & 63, wv = tid >> 6;
    __shared__ float red[4];
    const int d0 = tid * 4;
    ushort4 h4 = *(const ushort4*)(H + (size_t)r * 1024 + d0);
    float4 w4 = *(const float4*)(w2 + d0);
    float s = b2f(h4.x) * w4.x + b2f(h4.y) * w4.y
            + b2f(h4.z) * w4.z + b2f(h4.w) * w4.w;
    #pragma unroll
    for (int off = 32; off > 0; off >>= 1) s += __shfl_down(s, off);
    if (lane == 0) red[wv] = s;
    __syncthreads();
    if (tid == 0) out[r] = red[0] + red[1] + red[2] + red[3] + b2[0];
}

// per-b: softmax over N, cap/redistribute, imp; fused = sum_n imp*updated
__global__ __launch_bounds__(256) void imp_fused_k(
    const float* __restrict__ logits, const float* __restrict__ upd,
    float* __restrict__ imp_out, float* __restrict__ fused_out)
{
    const int b = blockIdx.x;
    const int tid = threadIdx.x;
    __shared__ float w[7];
    if (tid == 0) {
        float l[7], e[7];
        float mx = -1e30f;
        for (int i = 0; i < 7; ++i) { l[i] = logits[b * 7 + i]; mx = fmaxf(mx, l[i]); }
        float s = 0.f;
        for (int i = 0; i < 7; ++i) { e[i] = expf(l[i] - mx); s += e[i]; }
        float inv = 1.0f / s;
        float imp[7];
        for (int i = 0; i < 7; ++i) imp[i] = e[i] * inv;
        const float cap[7] = {1.f, 1.f, 1.f, 0.26f, 1.f, 1.f, 0.24f};
        const float fr[7]  = {1.f, 1.f, 1.f, 0.f,   1.f, 1.f, 0.f};
        float capped[7], capsum = 0.f, fmass = 0.f;
        for (int i = 0; i < 7; ++i) {
            capped[i] = fminf(imp[i], cap[i]);
            capsum += capped[i];
            fmass += imp[i] * fr[i];
        }
        float residual = fmaxf(1.0f - capsum, 0.0f);
        float redis[7], rs = 0.f;
        for (int i = 0; i < 7; ++i) {
            float fs = (fmass > 1e-6f) ? imp[i] * fr[i] / fmaxf(fmass, 1e-6f)
                                       : fr[i] * 0.2f;
            redis[i] = capped[i] + fs * residual;
            rs += redis[i];
        }
        float invr = 1.0f / fmaxf(rs, 1e-6f);
        for (int i = 0; i < 7; ++i) {
            float wi = redis[i] * invr;
            w[i] = wi;
            imp_out[b * 7 + i] = wi;
        }
    }
    __syncthreads();
    float wr[7];
    #pragma unroll
    for (int i = 0; i < 7; ++i) wr[i] = w[i];
    #pragma unroll
    for (int j = 0; j < 4; ++j) {
        int d = tid + j * 256;
        float s = 0.f;
        #pragma unroll
        for (int nn2 = 0; nn2 < 7; ++nn2)
            s += wr[nn2] * upd[(size_t)(b * 7 + nn2) * 1024 + d];
        fused_out[(size_t)b * 1024 + d] = s;
    }
}

__global__ __launch_bounds__(256) void physics_k(
    const float* __restrict__ upd, const float* __restrict__ fused,
    float* __restrict__ accums)
{
    const int b = blockIdx.x;
    const int tid = threadIdx.x;
    const int lane = tid & 63, wv = tid >> 6;
    __shared__ float u[7][1024];
    __shared__ float f[1024];
    __shared__ float wred[4][36];
    for (int idx = tid; idx < 7 * 1024; idx += 256)
        u[idx >> 10][idx & 1023] = upd[(size_t)b * 7168 + idx];
    for (int d = tid; d < 1024; d += 256)
        f[d] = fused[(size_t)b * 1024 + d];
    __syncthreads();

    float vals[36];
    #pragma unroll
    for (int i = 0; i < 36; ++i) vals[i] = 0.f;
    for (int d = tid; d < 1024; d += 256) {
        float x[7];
        #pragma unroll
        for (int n = 0; n < 7; ++n) x[n] = u[n][d];
        float fv = f[d];
        int idx = 0;
        #pragma unroll
        for (int n = 0; n < 7; ++n) {
            #pragma unroll
            for (int m = n; m < 7; ++m) vals[idx++] += x[n] * x[m];
        }
        #pragma unroll
        for (int n = 0; n < 7; ++n) vals[28 + n] += x[n] * fv;
        vals[35] += fv * fv;
    }
    #pragma unroll
    for (int i = 0; i < 36; ++i) {
        float s = vals[i];
        #pragma unroll
        for (int off = 32; off > 0; off >>= 1) s += __shfl_down(s, off);
        if (lane == 0) wred[wv][i] = s;
    }
    __syncthreads();
    if (tid == 0) {
        float tv[36];
        for (int i = 0; i < 36; ++i)
            tv[i] = wred[0][i] + wred[1][i] + wred[2][i] + wred[3][i];
        auto didx = [](int n, int m) -> int {
            if (n > m) { int t = n; n = m; m = t; }
            return n * 7 - n * (n - 1) / 2 + (m - n);
        };
        float norms[7];
        for (int n = 0; n < 7; ++n) norms[n] = sqrtf(tv[didx(n, n)]);
        float e = 0.f, nl = 0.f;
        for (int n = 0; n < 7; ++n)
            for (int m = 0; m < 7; ++m) {
                float cos_ = tv[didx(n, m)] / fmaxf(norms[n] * norms[m], 1e-8f);
                float adj = c_adj[n * 7 + m];
                e += (1.0f - cos_) * adj;
                if (adj == 0.0f && n != m) nl += fmaxf(cos_ - 0.35f, 0.0f);
            }
        float fnorm = sqrtf(tv[35]);
        float al = 0.f;
        for (int n = 0; n < 7; ++n) {
            float cosn = tv[28 + n] /
                         (fmaxf(norms[n], 1e-12f) * fmaxf(fnorm, 1e-12f));
            al += 1.0f - cosn;
        }
        atomicAdd(&accums[0], e);
        atomicAdd(&accums[1], nl);
        atomicAdd(&accums[2], al);
    }
}

__global__ void finalize_k(const float* __restrict__ a,
                           float* __restrict__ phys_o,
                           float* __restrict__ align_o)
{
    phys_o[0]  = a[0] / 41.0f + 0.5f * (a[1] / 8.0f);
    align_o[0] = a[2] * (1.0f / 7168.0f);
}

extern "C" void kernel_launch(void* const* d_in, const int* in_sizes, int n_in,
                              void* d_out, int out_size, void* d_ws, size_t ws_size,
                              hipStream_t stream)
{
    const float* nodes = (const float*)d_in[0];
    const float* Wq  = (const float*)d_in[1];
    const float* bq  = (const float*)d_in[2];
    const float* Wk  = (const float*)d_in[3];
    const float* bk  = (const float*)d_in[4];
    const float* Wv  = (const float*)d_in[5];
    const float* bv  = (const float*)d_in[6];
    const float* We1 = (const float*)d_in[7];
    const float* be1 = (const float*)d_in[8];
    const float* We2 = (const float*)d_in[9];
    const float* be2 = (const float*)d_in[10];
    const float* Wu1 = (const float*)d_in[11];
    const float* bu1 = (const float*)d_in[12];
    const float* Wu2 = (const float*)d_in[13];
    const float* bu2 = (const float*)d_in[14];
    const float* Wi1 = (const float*)d_in[15];
    const float* bi1 = (const float*)d_in[16];
    const float* Wi2 = (const float*)d_in[17];
    const float* bi2 = (const float*)d_in[18];

    float* out = (float*)d_out;
    float* fused_o = out;                            // 1,048,576
    float* upd_o   = out + 1048576;                  // 7,340,032
    float* imp_o   = out + 1048576 + 7340032;        // 7,168
    float* attn_o  = imp_o + 7168;                   // 50,176
    float* phys_o  = attn_o + 50176;                 // 1
    float* align_o = phys_o + 1;                     // 1

    const size_t BIG = 7340032;   // B*N*D
    const size_t MEG = 1048576;   // D*D
    char* p = (char*)d_ws;
    unsigned short* nodes_b = (unsigned short*)p; p += BIG * 2;
    unsigned short* qb      = (unsigned short*)p; p += BIG * 2;   // seg 0; reused: h_u
    unsigned short* kb      = (unsigned short*)p; p += BIG * 2;   // seg 1; reused: upd_b
    unsigned short* vb      = (unsigned short*)p; p += BIG * 2;   // seg 2; reused: h_i
    unsigned short* lab     = (unsigned short*)p; p += BIG * 2;   // seg 3; reused: msg
    unsigned short* rbb     = (unsigned short*)p; p += BIG * 2;   // seg 4
    unsigned short* WT_all  = (unsigned short*)p; p += (size_t)6144 * 1024 * 2;
    unsigned short* Wu1T    = (unsigned short*)p; p += 2 * MEG * 2;
    unsigned short* Wu2T    = (unsigned short*)p; p += MEG * 2;
    unsigned short* Wi1T    = (unsigned short*)p; p += 2 * MEG * 2;
    float* bias_all = (float*)p; p += 5120 * 4;
    float* ccf = (float*)p; p += MEG * 4;
    float* il  = (float*)p; p += 7168 * 4;
    float* acc = (float*)p; p += 4 * 4;
    unsigned short* msgb = lab;   // alias: safe (see attn_msg_b)
    unsigned short* hub  = qb;
    unsigned short* updb = kb;
    unsigned short* hib  = vb;

    dim3 blk(256);
    dim3 blk512(512);

    // prep
    cast_f2b<<<dim3(7168), blk, 0, stream>>>(nodes, nodes_b, 7340032);
    tcast_all<<<dim3(32, 64, 9), blk, 0, stream>>>(Wq, Wk, Wv, We1, Wu1, Wu2, Wi1,
                                                   WT_all, Wu1T, Wu2T, Wi1T);
    build_bias<<<dim3(20), blk, 0, stream>>>(bq, bk, bv, bias_all, acc);

    // fused q|k|v|la|rb : N=5120, segmented bf16 out into qb..rbb
    gemm128x8w<<<dim3(40, 56), blk512, 0, stream>>>(
        nodes_b, 0, nullptr, 0, WT_all, 1024, bias_all, nullptr,
        nullptr, qb, BIG, 1024, 0);

    // cc = nodes[:,-1] @ Wc + be1 (fp32 out), WcT at WT_all row 5120
    gemm64x128<<<dim3(8, 16), blk, 0, stream>>>(
        nodes_b, 1, nullptr, 0, WT_all + (size_t)5120 * 1024, 1024, be1, nullptr,
        ccf, nullptr, 1024, 0);

    // attention + messages (msg overwrites la)
    attn_msg_b<<<dim3(7168), blk, 0, stream>>>(qb, kb, vb, lab, rbb, ccf, We2, be2,
                                               attn_o, msgb);

    // h_u = gelu([nodes|msg] @ Wu1 + bu1)
    gemm128x8w<<<dim3(8, 56), blk512, 0, stream>>>(
        nodes_b, 0, msgb, 0, Wu1T, 2048, bu1, nullptr, nullptr, hub, 0, 2048, 1);
    // updated = h_u @ Wu2 + bu2 + nodes (fp32 out + bf16 copy)
    gemm128x8w<<<dim3(8, 56), blk512, 0, stream>>>(
        hub, 0, nullptr, 0, Wu2T, 1024, bu2, nodes, upd_o, updb, 0, 1024, 0);
    // h_i = gelu([updated|ctx] @ Wi1 + bi1)
    gemm128x8w<<<dim3(8, 56), blk512, 0, stream>>>(
        updb, 0, updb, 2, Wi1T, 2048, bi1, nullptr, nullptr, hib, 0, 2048, 1);

    // tail
    row_dot_b<<<dim3(7168), blk, 0, stream>>>(hib, Wi2, bi2, il);
    imp_fused_k<<<dim3(1024), blk, 0, stream>>>(il, upd_o, imp_o, fused_o);
    physics_k<<<dim3(1024), blk, 0, stream>>>(upd_o, fused_o, acc);
    finalize_k<<<1, 1, 0, stream>>>(acc, phys_o, align_o);
}